// Round 5
// baseline (820.617 us; speedup 1.0000x reference)
//
#include <hip/hip_runtime.h>
#include <hip/hip_fp16.h>
#include <math.h>
#include <stdint.h>

#define NEG_SLOPE 0.2f

// ---------- DPP helpers: sum within each 16-lane row (zero DS ops) ----------
template<int CTRL>
__device__ __forceinline__ float dpp_add(float x) {
    union { float f; int i; } u, v;
    u.f = x;
    v.i = __builtin_amdgcn_update_dpp(0, u.i, CTRL, 0xF, 0xF, true);
    return x + v.f;
}
__device__ __forceinline__ float reduce16(float x) {
    x = dpp_add<0xB1>(x);   // quad_perm xor1
    x = dpp_add<0x4E>(x);   // quad_perm xor2
    x = dpp_add<0x124>(x);  // row_ror:4
    x = dpp_add<0x128>(x);  // row_ror:8
    return x;
}

// ---------- transpose pair ----------
__global__ void k_transpose_pair(const float* __restrict__ Wl,
                                 const float* __restrict__ Wr,
                                 float* __restrict__ wt, int K) {
    int i = blockIdx.x * 256 + threadIdx.x;
    if (i < 128 * K) {
        int c = i / K, k = i - c * K;
        wt[k * 256 + c]       = Wl[i];
        wt[k * 256 + 128 + c] = Wr[i];
    }
}

// ---------- GEMM ----------
template<int K>
__global__ __launch_bounds__(256) void k_gemm2(
    const float* __restrict__ X, const float* __restrict__ Wt,
    const float* __restrict__ bl, const float* __restrict__ br,
    float* __restrict__ Y, int N) {
    constexpr int LDSS = K + 4;
    __shared__ float xs[32 * LDSS];
    const int t = threadIdx.x;
    const int row0 = blockIdx.x * 32;
    for (int i = t; i < 32 * (K / 4); i += 256) {
        int r = i / (K / 4);
        int k4 = (i - r * (K / 4)) * 4;
        int gr = row0 + r;
        float4 v = make_float4(0.f, 0.f, 0.f, 0.f);
        if (gr < N) v = *reinterpret_cast<const float4*>(X + (size_t)gr * K + k4);
        *reinterpret_cast<float4*>(&xs[r * LDSS + k4]) = v;
    }
    __syncthreads();
    const int cg = t & 63, rg = t >> 6;
    const int c0 = cg * 4, r0 = rg * 8;
    float acc[8][4];
    {
        float b[4];
#pragma unroll
        for (int q = 0; q < 4; ++q) {
            int c = c0 + q;
            b[q] = (c < 128) ? bl[c] : br[c - 128];
        }
#pragma unroll
        for (int r = 0; r < 8; ++r)
#pragma unroll
            for (int q = 0; q < 4; ++q) acc[r][q] = b[q];
    }
    for (int k = 0; k < K; k += 4) {
        float xv[8][4];
#pragma unroll
        for (int r = 0; r < 8; ++r)
            *reinterpret_cast<float4*>(xv[r]) =
                *reinterpret_cast<const float4*>(&xs[(r0 + r) * LDSS + k]);
#pragma unroll
        for (int kk = 0; kk < 4; ++kk) {
            float4 w = *reinterpret_cast<const float4*>(Wt + (size_t)(k + kk) * 256 + c0);
#pragma unroll
            for (int r = 0; r < 8; ++r) {
                acc[r][0] = fmaf(xv[r][kk], w.x, acc[r][0]);
                acc[r][1] = fmaf(xv[r][kk], w.y, acc[r][1]);
                acc[r][2] = fmaf(xv[r][kk], w.z, acc[r][2]);
                acc[r][3] = fmaf(xv[r][kk], w.w, acc[r][3]);
            }
        }
    }
#pragma unroll
    for (int r = 0; r < 8; ++r) {
        int gr = row0 + r0 + r;
        if (gr < N)
            *reinterpret_cast<float4*>(Y + (size_t)gr * 256 + c0) =
                make_float4(acc[r][0], acc[r][1], acc[r][2], acc[r][3]);
    }
}

// ---------------- CSR build ----------------
__global__ void k_init_cnt(int* __restrict__ cnt, int N) {
    int i = blockIdx.x * 256 + threadIdx.x;
    if (i < N) cnt[i] = 1;
}
__global__ void k_count(const int* __restrict__ dstArr, int* __restrict__ cnt, int E) {
    int e = blockIdx.x * 256 + threadIdx.x;
    if (e < E) atomicAdd(&cnt[dstArr[e]], 1);
}
__global__ void k_scan_block(const int* __restrict__ v_in, int* __restrict__ excl,
                             int* __restrict__ bsums, int N) {
    __shared__ int sh[256];
    int tid = threadIdx.x;
    int i = blockIdx.x * 256 + tid;
    int v = (i < N) ? v_in[i] : 0;
    sh[tid] = v;
    __syncthreads();
    for (int off = 1; off < 256; off <<= 1) {
        int add = (tid >= off) ? sh[tid - off] : 0;
        __syncthreads();
        sh[tid] += add;
        __syncthreads();
    }
    if (i < N) excl[i] = sh[tid] - v;
    if (tid == 255) bsums[blockIdx.x] = sh[255];
}
__global__ void k_scan_top(const int* __restrict__ bsums, int* __restrict__ boff,
                           int nb, int* __restrict__ rowptr, int N) {
    __shared__ int sh[256];
    int tid = threadIdx.x;
    int v = (tid < nb) ? bsums[tid] : 0;
    sh[tid] = v;
    __syncthreads();
    for (int off = 1; off < 256; off <<= 1) {
        int add = (tid >= off) ? sh[tid - off] : 0;
        __syncthreads();
        sh[tid] += add;
        __syncthreads();
    }
    if (tid < nb) boff[tid] = sh[tid] - v;
    if (tid == 255) rowptr[N] = sh[255];
}
__global__ void k_scan_add(int* __restrict__ rowptr, const int* __restrict__ boff, int N) {
    int i = blockIdx.x * 256 + threadIdx.x;
    if (i < N) rowptr[i] += boff[blockIdx.x];
}
__global__ void k_csr_self(const int* __restrict__ rowptr, int* __restrict__ csr, int N) {
    int i = blockIdx.x * 256 + threadIdx.x;
    if (i < N) csr[rowptr[i]] = i;
}
// bucket bases from rowptr: base[b] = rowptr[min(b*64,N)] - min(b*64,N)
// (subtracting the self-loops of preceding nodes); also zero bucket fill.
__global__ void k_bucket_base(const int* __restrict__ rowptr, int* __restrict__ base,
                              int* __restrict__ bfill, int NB, int N) {
    int b = blockIdx.x * 256 + threadIdx.x;
    if (b <= NB) {
        int node = min(b * 64, N);
        base[b] = rowptr[node] - node;
        if (b < NB) bfill[b] = 0;
    }
}
// Phase A: scatter packed (src | local_dst<<20) into per-bucket contiguous runs.
__global__ void k_bucket_scatter(const int* __restrict__ ei, const int* __restrict__ base,
                                 int* __restrict__ bfill, uint32_t* __restrict__ tmp, int E) {
    int e = blockIdx.x * 256 + threadIdx.x;
    if (e < E) {
        int s = ei[e];
        int d = ei[E + e];
        int b = d >> 6, ld = d & 63;
        int pos = base[b] + atomicAdd(&bfill[b], 1);
        tmp[pos] = (uint32_t)s | ((uint32_t)ld << 20);
    }
}
// Phase B: one block per bucket; writes land in a ~4KB contiguous csr window.
__global__ __launch_bounds__(256) void k_bucket_fill(
    const uint32_t* __restrict__ tmp, const int* __restrict__ base,
    const int* __restrict__ rowptr, int* __restrict__ csr, int N) {
    __shared__ int lf[64];
    __shared__ int rp[64];
    int b = blockIdx.x, t = threadIdx.x;
    int n0 = b * 64;
    if (t < 64) {
        lf[t] = 1;  // slot 0 reserved for self-loop
        rp[t] = (n0 + t < N) ? rowptr[n0 + t] : 0;
    }
    __syncthreads();
    int s0 = base[b], s1 = base[b + 1];
    for (int i = s0 + t; i < s1; i += 256) {
        uint32_t pk = tmp[i];
        int src = (int)(pk & 0xFFFFFu);
        int ld  = (int)(pk >> 20);
        int slot = atomicAdd(&lf[ld], 1);
        csr[rp[ld] + slot] = src;
    }
}

// ---------------- prep: fp16-pack xl + per-head linear att dots ------------
__global__ __launch_bounds__(256) void k_prep(
    const float* __restrict__ xlr, const float* __restrict__ att,
    uint32_t* __restrict__ xlh, float* __restrict__ dl, float* __restrict__ dr,
    int N) {
    int wid = threadIdx.x >> 6, lane = threadIdx.x & 63;
    int n = blockIdx.x * 4 + wid;
    if (n >= N) return;
    int h = lane >> 4, j = lane & 15;
    int c0 = h * 32 + j, c1 = c0 + 16;
    const float* row = xlr + (size_t)n * 256;
    float xl0 = row[c0], xl1 = row[c1];
    float xr0 = row[128 + c0], xr1 = row[128 + c1];
    float a0 = att[c0], a1 = att[c1];
    __half2 hp = __floats2half2_rn(xl0, xl1);
    xlh[(size_t)n * 64 + lane] = *reinterpret_cast<uint32_t*>(&hp);
    float pl = reduce16(fmaf(a0, xl0, a1 * xl1));
    float pr = reduce16(fmaf(a0, xr0, a1 * xr1));
    if (j == 0) {
        dl[n * 4 + h] = 0.6f * pl;
        dr[n * 4 + h] = 0.6f * pr;
    }
}

// ---------------- fused GATv2 edge kernel ----------------
__global__ __launch_bounds__(256) void k_gat_edge(
    const float* __restrict__ xlr, const uint32_t* __restrict__ xlh,
    const float* __restrict__ dl, const float* __restrict__ dr,
    const float* __restrict__ att, const float* __restrict__ bias,
    const int* __restrict__ rowptr, const int* __restrict__ csr,
    float* __restrict__ out, int N, int relu_flag) {
    int wid = threadIdx.x >> 6;
    int lane = threadIdx.x & 63;
    int n = blockIdx.x * 4 + wid;
    if (n >= N) return;
    const int h = lane >> 4, j = lane & 15;
    const int c0 = h * 32 + j, c1 = c0 + 16;
    float xr0 = xlr[(size_t)n * 256 + 128 + c0];
    float xr1 = xlr[(size_t)n * 256 + 128 + c1];
    float a0 = att[c0], a1 = att[c1];
    float drh = dr[n * 4 + h];
    float ssum = 0.f, acc0 = 0.f, acc1 = 0.f;
    int beg = rowptr[n], end = rowptr[n + 1];
    int i = beg;
    for (; i + 3 < end; i += 4) {
        int s[4];
#pragma unroll
        for (int e = 0; e < 4; ++e) s[e] = csr[i + e];
        uint32_t q[4];
        float dv[4];
#pragma unroll
        for (int e = 0; e < 4; ++e) {
            q[e] = xlh[(size_t)s[e] * 64 + lane];
            dv[e] = dl[s[e] * 4 + h] + drh;
        }
#pragma unroll
        for (int e = 0; e < 4; ++e) {
            __half2 hv = *reinterpret_cast<__half2*>(&q[e]);
            float A0 = __low2float(hv), A1 = __high2float(hv);
            float p = fmaf(a0, fabsf(A0 + xr0), a1 * fabsf(A1 + xr1));
            p = reduce16(p);
            float alpha = fmaf(0.4f, p, dv[e]);
            float w = __expf(alpha);
            ssum += w;
            acc0 = fmaf(w, A0, acc0);
            acc1 = fmaf(w, A1, acc1);
        }
    }
    for (; i < end; ++i) {
        int sA = csr[i];
        uint32_t qA = xlh[(size_t)sA * 64 + lane];
        float dA = dl[sA * 4 + h] + drh;
        __half2 hv = *reinterpret_cast<__half2*>(&qA);
        float A0 = __low2float(hv), A1 = __high2float(hv);
        float p = fmaf(a0, fabsf(A0 + xr0), a1 * fabsf(A1 + xr1));
        p = reduce16(p);
        float alpha = fmaf(0.4f, p, dA);
        float w = __expf(alpha);
        ssum += w;
        acc0 = fmaf(w, A0, acc0);
        acc1 = fmaf(w, A1, acc1);
    }
    float inv = 1.f / (ssum + 1e-16f);
    float o0 = acc0 * inv + bias[c0];
    float o1 = acc1 * inv + bias[c1];
    if (relu_flag) { o0 = fmaxf(o0, 0.f); o1 = fmaxf(o1, 0.f); }
    out[(size_t)n * 128 + c0] = o0;
    out[(size_t)n * 128 + c1] = o1;
}

// ---------------- pooling ----------------
__global__ void k_zero(float* __restrict__ p, int n) {
    int i = blockIdx.x * 256 + threadIdx.x;
    if (i < n) p[i] = 0.f;
}
__global__ __launch_bounds__(128) void k_pool(
    const float* __restrict__ h, const int* __restrict__ batch,
    float* __restrict__ pool, float* __restrict__ gcnt, int N) {
    const int NPB = 32;
    int c = threadIdx.x;
    int n0 = blockIdx.x * NPB;
    int n1 = min(n0 + NPB, N);
    float acc = 0.f;
    int curg = -1, cntl = 0;
    for (int n = n0; n < n1; ++n) {
        int g = batch[n];
        if (g != curg) {
            if (curg >= 0) {
                atomicAdd(&pool[curg * 128 + c], acc);
                if (c == 0) atomicAdd(&gcnt[curg], (float)cntl);
            }
            acc = 0.f; cntl = 0; curg = g;
        }
        acc += h[(size_t)n * 128 + c];
        cntl++;
    }
    if (curg >= 0) {
        atomicAdd(&pool[curg * 128 + c], acc);
        if (c == 0) atomicAdd(&gcnt[curg], (float)cntl);
    }
}
__global__ __launch_bounds__(64) void k_head(
    const float* __restrict__ pool, const float* __restrict__ gcnt,
    const float* __restrict__ Wlin, const float* __restrict__ blin,
    float* __restrict__ out, int G) {
    int g = blockIdx.x, l = threadIdx.x;
    float d = pool[g * 128 + l] * Wlin[l] + pool[g * 128 + l + 64] * Wlin[l + 64];
#pragma unroll
    for (int off = 32; off; off >>= 1) d += __shfl_xor(d, off, 64);
    if (l == 0) {
        float cnt = fmaxf(gcnt[g], 1.f);
        out[g] = d / cnt + blin[0];
    }
}

// ---------------- driver ----------------
extern "C" void kernel_launch(void* const* d_in, const int* in_sizes, int n_in,
                              void* d_out, int out_size, void* d_ws, size_t ws_size,
                              hipStream_t stream) {
    const float* x     = (const float*)d_in[0];
    const int*   ei    = (const int*)d_in[1];
    const int*   batch = (const int*)d_in[2];
    const float* Wl1   = (const float*)d_in[3];
    const float* bl1   = (const float*)d_in[4];
    const float* Wr1   = (const float*)d_in[5];
    const float* br1   = (const float*)d_in[6];
    const float* att1  = (const float*)d_in[7];
    const float* bias1 = (const float*)d_in[8];
    const float* Wl2   = (const float*)d_in[9];
    const float* bl2   = (const float*)d_in[10];
    const float* Wr2   = (const float*)d_in[11];
    const float* br2   = (const float*)d_in[12];
    const float* att2  = (const float*)d_in[13];
    const float* bias2 = (const float*)d_in[14];
    const float* Wlin  = (const float*)d_in[15];
    const float* blin  = (const float*)d_in[16];

    const int N   = in_sizes[2];
    const int E   = in_sizes[1] / 2;
    const int Fin = in_sizes[0] / N;     // 256
    const int G   = out_size;            // 64
    (void)n_in; (void)ws_size;

    char* p = (char*)d_ws;
    auto alloc = [&](size_t bytes) -> char* {
        char* r = p;
        p += (bytes + 255) & ~(size_t)255;
        return r;
    };
    float*    xlr   = (float*)alloc((size_t)N * 256 * 4);
    float*    hb    = (float*)alloc((size_t)N * 128 * 4);
    float*    wt    = (float*)alloc((size_t)Fin * 256 * 4);
    uint32_t* xlh   = (uint32_t*)alloc((size_t)N * 64 * 4);
    float*    dl    = (float*)alloc((size_t)N * 4 * 4);
    float*    dr    = (float*)alloc((size_t)N * 4 * 4);
    int*      cnt   = (int*)alloc((size_t)N * 4);
    int*      rowptr= (int*)alloc((size_t)(N + 1) * 4);
    int*      bsums = (int*)alloc(256 * 4);
    int*      boff  = (int*)alloc(256 * 4);
    int*      csr   = (int*)alloc((size_t)(E + N) * 4);
    float*    pool  = (float*)alloc((size_t)G * 128 * 4);
    float*    gcnt  = (float*)alloc((size_t)G * 4);
    const int NB = (N + 63) / 64;        // dst buckets of 64 nodes
    int*      bbase = (int*)alloc((size_t)(NB + 1) * 4);
    int*      bfill = (int*)alloc((size_t)NB * 4);
    // tmp bucket-sorted packed edges (E u32) aliases xlr: CSR build completes
    // before the first GEMM writes xlr.
    uint32_t* tmp = (uint32_t*)xlr;

    const int nb = (N + 255) / 256;
    const int eb = (E + 255) / 256;
    const int wb = (N + 3) / 4;

    // ---- CSR by dst (self-loop in slot 0), bucketed for write locality ----
    k_init_cnt<<<nb, 256, 0, stream>>>(cnt, N);
    k_count<<<eb, 256, 0, stream>>>(ei + E, cnt, E);
    k_scan_block<<<nb, 256, 0, stream>>>(cnt, rowptr, bsums, N);
    k_scan_top<<<1, 256, 0, stream>>>(bsums, boff, nb, rowptr, N);
    k_scan_add<<<nb, 256, 0, stream>>>(rowptr, boff, N);
    k_bucket_base<<<(NB + 256) / 256, 256, 0, stream>>>(rowptr, bbase, bfill, NB, N);
    k_bucket_scatter<<<eb, 256, 0, stream>>>(ei, bbase, bfill, tmp, E);
    k_csr_self<<<nb, 256, 0, stream>>>(rowptr, csr, N);
    k_bucket_fill<<<NB, 256, 0, stream>>>(tmp, bbase, rowptr, csr, N);

    // ---- layer 1 ----
    k_transpose_pair<<<(128 * Fin + 255) / 256, 256, 0, stream>>>(Wl1, Wr1, wt, Fin);
    k_gemm2<256><<<(N + 31) / 32, 256, 0, stream>>>(x, wt, bl1, br1, xlr, N);
    k_prep<<<wb, 256, 0, stream>>>(xlr, att1, xlh, dl, dr, N);
    k_gat_edge<<<wb, 256, 0, stream>>>(xlr, xlh, dl, dr, att1, bias1, rowptr, csr, hb, N, 1);

    // ---- layer 2 ----
    k_transpose_pair<<<(128 * 128 + 255) / 256, 256, 0, stream>>>(Wl2, Wr2, wt, 128);
    k_gemm2<128><<<(N + 31) / 32, 256, 0, stream>>>(hb, wt, bl2, br2, xlr, N);
    k_prep<<<wb, 256, 0, stream>>>(xlr, att2, xlh, dl, dr, N);
    k_gat_edge<<<wb, 256, 0, stream>>>(xlr, xlh, dl, dr, att2, bias2, rowptr, csr, hb, N, 0);

    // ---- pool + head ----
    k_zero<<<(G * 128 + 255) / 256, 256, 0, stream>>>(pool, G * 128);
    k_zero<<<1, 64, 0, stream>>>(gcnt, G);
    k_pool<<<(N + 31) / 32, 128, 0, stream>>>(hb, batch, pool, gcnt, N);
    k_head<<<G, 64, 0, stream>>>(pool, gcnt, Wlin, blin, (float*)d_out, G);
}

// Round 6
// 514.852 us; speedup vs baseline: 1.5939x; 1.5939x over previous
//
#include <hip/hip_runtime.h>
#include <hip/hip_fp16.h>
#include <math.h>
#include <stdint.h>

#define NEG_SLOPE 0.2f
#define EPB 4096          // edges per block in partition kernels
#define NBKT 128          // bucket space (dst>>9; 98 used for N=50000)

// ---------- DPP helpers: sum within each 16-lane row (zero DS ops) ----------
template<int CTRL>
__device__ __forceinline__ float dpp_add(float x) {
    union { float f; int i; } u, v;
    u.f = x;
    v.i = __builtin_amdgcn_update_dpp(0, u.i, CTRL, 0xF, 0xF, true);
    return x + v.f;
}
__device__ __forceinline__ float reduce16(float x) {
    x = dpp_add<0xB1>(x);   // quad_perm xor1
    x = dpp_add<0x4E>(x);   // quad_perm xor2
    x = dpp_add<0x124>(x);  // row_ror:4
    x = dpp_add<0x128>(x);  // row_ror:8
    return x;
}

// ---------- transpose pair ----------
__global__ void k_transpose_pair(const float* __restrict__ Wl,
                                 const float* __restrict__ Wr,
                                 float* __restrict__ wt, int K) {
    int i = blockIdx.x * 256 + threadIdx.x;
    if (i < 128 * K) {
        int c = i / K, k = i - c * K;
        wt[k * 256 + c]       = Wl[i];
        wt[k * 256 + 128 + c] = Wr[i];
    }
}

// ---------- GEMM ----------
template<int K>
__global__ __launch_bounds__(256) void k_gemm2(
    const float* __restrict__ X, const float* __restrict__ Wt,
    const float* __restrict__ bl, const float* __restrict__ br,
    float* __restrict__ Y, int N) {
    constexpr int LDSS = K + 4;
    __shared__ float xs[32 * LDSS];
    const int t = threadIdx.x;
    const int row0 = blockIdx.x * 32;
    for (int i = t; i < 32 * (K / 4); i += 256) {
        int r = i / (K / 4);
        int k4 = (i - r * (K / 4)) * 4;
        int gr = row0 + r;
        float4 v = make_float4(0.f, 0.f, 0.f, 0.f);
        if (gr < N) v = *reinterpret_cast<const float4*>(X + (size_t)gr * K + k4);
        *reinterpret_cast<float4*>(&xs[r * LDSS + k4]) = v;
    }
    __syncthreads();
    const int cg = t & 63, rg = t >> 6;
    const int c0 = cg * 4, r0 = rg * 8;
    float acc[8][4];
    {
        float b[4];
#pragma unroll
        for (int q = 0; q < 4; ++q) {
            int c = c0 + q;
            b[q] = (c < 128) ? bl[c] : br[c - 128];
        }
#pragma unroll
        for (int r = 0; r < 8; ++r)
#pragma unroll
            for (int q = 0; q < 4; ++q) acc[r][q] = b[q];
    }
    for (int k = 0; k < K; k += 4) {
        float xv[8][4];
#pragma unroll
        for (int r = 0; r < 8; ++r)
            *reinterpret_cast<float4*>(xv[r]) =
                *reinterpret_cast<const float4*>(&xs[(r0 + r) * LDSS + k]);
#pragma unroll
        for (int kk = 0; kk < 4; ++kk) {
            float4 w = *reinterpret_cast<const float4*>(Wt + (size_t)(k + kk) * 256 + c0);
#pragma unroll
            for (int r = 0; r < 8; ++r) {
                acc[r][0] = fmaf(xv[r][kk], w.x, acc[r][0]);
                acc[r][1] = fmaf(xv[r][kk], w.y, acc[r][1]);
                acc[r][2] = fmaf(xv[r][kk], w.z, acc[r][2]);
                acc[r][3] = fmaf(xv[r][kk], w.w, acc[r][3]);
            }
        }
    }
#pragma unroll
    for (int r = 0; r < 8; ++r) {
        int gr = row0 + r0 + r;
        if (gr < N)
            *reinterpret_cast<float4*>(Y + (size_t)gr * 256 + c0) =
                make_float4(acc[r][0], acc[r][1], acc[r][2], acc[r][3]);
    }
}

// ---------------- CSR build: degree + rowptr ----------------
__global__ void k_init_cnt(int* __restrict__ cnt, int N) {
    int i = blockIdx.x * 256 + threadIdx.x;
    if (i < N) cnt[i] = 1;
}
__global__ void k_count(const int* __restrict__ dstArr, int* __restrict__ cnt, int E) {
    int e = blockIdx.x * 256 + threadIdx.x;
    if (e < E) atomicAdd(&cnt[dstArr[e]], 1);
}
__global__ void k_scan_block(const int* __restrict__ v_in, int* __restrict__ excl,
                             int* __restrict__ bsums, int N) {
    __shared__ int sh[256];
    int tid = threadIdx.x;
    int i = blockIdx.x * 256 + tid;
    int v = (i < N) ? v_in[i] : 0;
    sh[tid] = v;
    __syncthreads();
    for (int off = 1; off < 256; off <<= 1) {
        int add = (tid >= off) ? sh[tid - off] : 0;
        __syncthreads();
        sh[tid] += add;
        __syncthreads();
    }
    if (i < N) excl[i] = sh[tid] - v;
    if (tid == 255) bsums[blockIdx.x] = sh[255];
}
__global__ void k_scan_top(const int* __restrict__ bsums, int* __restrict__ boff,
                           int nb, int* __restrict__ rowptr, int N) {
    __shared__ int sh[256];
    int tid = threadIdx.x;
    int v = (tid < nb) ? bsums[tid] : 0;
    sh[tid] = v;
    __syncthreads();
    for (int off = 1; off < 256; off <<= 1) {
        int add = (tid >= off) ? sh[tid - off] : 0;
        __syncthreads();
        sh[tid] += add;
        __syncthreads();
    }
    if (tid < nb) boff[tid] = sh[tid] - v;
    if (tid == 255) rowptr[N] = sh[255];
}
__global__ void k_scan_add(int* __restrict__ rowptr, const int* __restrict__ boff, int N) {
    int i = blockIdx.x * 256 + threadIdx.x;
    if (i < N) rowptr[i] += boff[blockIdx.x];
}
__global__ void k_csr_self(const int* __restrict__ rowptr, int* __restrict__ csr, int N) {
    int i = blockIdx.x * 256 + threadIdx.x;
    if (i < N) csr[rowptr[i]] = i;
}

// ---------------- radix partition by dst>>9 (scan-based, no global RMW) ----
// A1: per-block LDS histogram -> g_hist[block][NBKT]
__global__ __launch_bounds__(256) void k_hist(const int* __restrict__ dstArr,
                                              int* __restrict__ g_hist, int E) {
    __shared__ int h[NBKT];
    int t = threadIdx.x;
    if (t < NBKT) h[t] = 0;
    __syncthreads();
    int s0 = blockIdx.x * EPB, s1 = min(E, s0 + EPB);
    for (int i = s0 + t; i < s1; i += 256) atomicAdd(&h[dstArr[i] >> 9], 1);
    __syncthreads();
    if (t < NBKT) g_hist[blockIdx.x * NBKT + t] = h[t];
}
// A2: g_base[block][b] = bucketStart[b] + sum_{i<block} g_hist[i][b]
__global__ __launch_bounds__(512) void k_part_scan(const int* __restrict__ g_hist,
                                                   int* __restrict__ g_base, int NB1) {
    __shared__ int csum[4][NBKT];
    __shared__ int btot[NBKT];
    __shared__ int bstart[NBKT];
    int tid = threadIdx.x, c = tid >> 7, b = tid & (NBKT - 1);
    int chunk = (NB1 + 3) >> 2;
    int i0 = c * chunk, i1 = min(NB1, i0 + chunk);
    int run = 0;
#pragma unroll 4
    for (int i = i0; i < i1; ++i) run += g_hist[i * NBKT + b];
    csum[c][b] = run;
    __syncthreads();
    int mytot = 0;
    if (c == 0) {
        mytot = csum[0][b] + csum[1][b] + csum[2][b] + csum[3][b];
        btot[b] = mytot;
    }
    __syncthreads();
    for (int off = 1; off < NBKT; off <<= 1) {
        int add = 0;
        if (c == 0 && b >= off) add = btot[b - off];
        __syncthreads();
        if (c == 0) btot[b] += add;
        __syncthreads();
    }
    if (c == 0) bstart[b] = btot[b] - mytot;  // exclusive
    __syncthreads();
    int base = bstart[b];
    for (int cc = 0; cc < c; ++cc) base += csum[cc][b];
    run = base;
#pragma unroll 4
    for (int i = i0; i < i1; ++i) {
        g_base[i * NBKT + b] = run;
        run += g_hist[i * NBKT + b];
    }
}
// A3: scatter packed (src<<16|dst) into per-(block,bucket) contiguous runs.
__global__ __launch_bounds__(256) void k_scatter(const int* __restrict__ ei,
                                                 const int* __restrict__ g_base,
                                                 uint32_t* __restrict__ tmp, int E) {
    __shared__ int off[NBKT];
    int t = threadIdx.x;
    if (t < NBKT) off[t] = g_base[blockIdx.x * NBKT + t];
    __syncthreads();
    int s0 = blockIdx.x * EPB, s1 = min(E, s0 + EPB);
    for (int i = s0 + t; i < s1; i += 256) {
        int s = ei[i], d = ei[E + i];
        int pos = atomicAdd(&off[d >> 9], 1);
        tmp[pos] = ((uint32_t)s << 16) | (uint32_t)d;
    }
}
// B: place from bucket-ordered tmp; per-node atomics (low contention),
// writes confined to a moving ~66KB csr window per block.
__global__ __launch_bounds__(256) void k_csr_place(const uint32_t* __restrict__ tmp,
                                                   int* __restrict__ fill,
                                                   const int* __restrict__ rowptr,
                                                   int* __restrict__ csr, int E, int chunk) {
    int s0 = blockIdx.x * chunk, s1 = min(E, s0 + chunk);
    for (int i = s0 + threadIdx.x; i < s1; i += 256) {
        uint32_t pk = tmp[i];
        int src = (int)(pk >> 16);
        int d   = (int)(pk & 0xFFFFu);
        int slot = atomicAdd(&fill[d], 1);
        csr[rowptr[d] + slot] = src;
    }
}

// ---------------- prep: fp16-pack xl + per-head linear att dots ------------
__global__ __launch_bounds__(256) void k_prep(
    const float* __restrict__ xlr, const float* __restrict__ att,
    uint32_t* __restrict__ xlh, float* __restrict__ dl, float* __restrict__ dr,
    int N) {
    int wid = threadIdx.x >> 6, lane = threadIdx.x & 63;
    int n = blockIdx.x * 4 + wid;
    if (n >= N) return;
    int h = lane >> 4, j = lane & 15;
    int c0 = h * 32 + j, c1 = c0 + 16;
    const float* row = xlr + (size_t)n * 256;
    float xl0 = row[c0], xl1 = row[c1];
    float xr0 = row[128 + c0], xr1 = row[128 + c1];
    float a0 = att[c0], a1 = att[c1];
    __half2 hp = __floats2half2_rn(xl0, xl1);
    xlh[(size_t)n * 64 + lane] = *reinterpret_cast<uint32_t*>(&hp);
    float pl = reduce16(fmaf(a0, xl0, a1 * xl1));
    float pr = reduce16(fmaf(a0, xr0, a1 * xr1));
    if (j == 0) {
        dl[n * 4 + h] = 0.6f * pl;
        dr[n * 4 + h] = 0.6f * pr;
    }
}

// ---------------- fused GATv2 edge kernel ----------------
__global__ __launch_bounds__(256) void k_gat_edge(
    const float* __restrict__ xlr, const uint32_t* __restrict__ xlh,
    const float* __restrict__ dl, const float* __restrict__ dr,
    const float* __restrict__ att, const float* __restrict__ bias,
    const int* __restrict__ rowptr, const int* __restrict__ csr,
    float* __restrict__ out, int N, int relu_flag) {
    int wid = threadIdx.x >> 6;
    int lane = threadIdx.x & 63;
    int n = blockIdx.x * 4 + wid;
    if (n >= N) return;
    const int h = lane >> 4, j = lane & 15;
    const int c0 = h * 32 + j, c1 = c0 + 16;
    float xr0 = xlr[(size_t)n * 256 + 128 + c0];
    float xr1 = xlr[(size_t)n * 256 + 128 + c1];
    float a0 = att[c0], a1 = att[c1];
    float drh = dr[n * 4 + h];
    float ssum = 0.f, acc0 = 0.f, acc1 = 0.f;
    int beg = rowptr[n], end = rowptr[n + 1];
    int i = beg;
    for (; i + 3 < end; i += 4) {
        int s[4];
#pragma unroll
        for (int e = 0; e < 4; ++e) s[e] = csr[i + e];
        uint32_t q[4];
        float dv[4];
#pragma unroll
        for (int e = 0; e < 4; ++e) {
            q[e] = xlh[(size_t)s[e] * 64 + lane];
            dv[e] = dl[s[e] * 4 + h] + drh;
        }
#pragma unroll
        for (int e = 0; e < 4; ++e) {
            __half2 hv = *reinterpret_cast<__half2*>(&q[e]);
            float A0 = __low2float(hv), A1 = __high2float(hv);
            float p = fmaf(a0, fabsf(A0 + xr0), a1 * fabsf(A1 + xr1));
            p = reduce16(p);
            float alpha = fmaf(0.4f, p, dv[e]);
            float w = __expf(alpha);
            ssum += w;
            acc0 = fmaf(w, A0, acc0);
            acc1 = fmaf(w, A1, acc1);
        }
    }
    for (; i < end; ++i) {
        int sA = csr[i];
        uint32_t qA = xlh[(size_t)sA * 64 + lane];
        float dA = dl[sA * 4 + h] + drh;
        __half2 hv = *reinterpret_cast<__half2*>(&qA);
        float A0 = __low2float(hv), A1 = __high2float(hv);
        float p = fmaf(a0, fabsf(A0 + xr0), a1 * fabsf(A1 + xr1));
        p = reduce16(p);
        float alpha = fmaf(0.4f, p, dA);
        float w = __expf(alpha);
        ssum += w;
        acc0 = fmaf(w, A0, acc0);
        acc1 = fmaf(w, A1, acc1);
    }
    float inv = 1.f / (ssum + 1e-16f);
    float o0 = acc0 * inv + bias[c0];
    float o1 = acc1 * inv + bias[c1];
    if (relu_flag) { o0 = fmaxf(o0, 0.f); o1 = fmaxf(o1, 0.f); }
    out[(size_t)n * 128 + c0] = o0;
    out[(size_t)n * 128 + c1] = o1;
}

// ---------------- pooling ----------------
__global__ void k_zero(float* __restrict__ p, int n) {
    int i = blockIdx.x * 256 + threadIdx.x;
    if (i < n) p[i] = 0.f;
}
__global__ __launch_bounds__(128) void k_pool(
    const float* __restrict__ h, const int* __restrict__ batch,
    float* __restrict__ pool, float* __restrict__ gcnt, int N) {
    const int NPB = 32;
    int c = threadIdx.x;
    int n0 = blockIdx.x * NPB;
    int n1 = min(n0 + NPB, N);
    float acc = 0.f;
    int curg = -1, cntl = 0;
    for (int n = n0; n < n1; ++n) {
        int g = batch[n];
        if (g != curg) {
            if (curg >= 0) {
                atomicAdd(&pool[curg * 128 + c], acc);
                if (c == 0) atomicAdd(&gcnt[curg], (float)cntl);
            }
            acc = 0.f; cntl = 0; curg = g;
        }
        acc += h[(size_t)n * 128 + c];
        cntl++;
    }
    if (curg >= 0) {
        atomicAdd(&pool[curg * 128 + c], acc);
        if (c == 0) atomicAdd(&gcnt[curg], (float)cntl);
    }
}
__global__ __launch_bounds__(64) void k_head(
    const float* __restrict__ pool, const float* __restrict__ gcnt,
    const float* __restrict__ Wlin, const float* __restrict__ blin,
    float* __restrict__ out, int G) {
    int g = blockIdx.x, l = threadIdx.x;
    float d = pool[g * 128 + l] * Wlin[l] + pool[g * 128 + l + 64] * Wlin[l + 64];
#pragma unroll
    for (int off = 32; off; off >>= 1) d += __shfl_xor(d, off, 64);
    if (l == 0) {
        float cnt = fmaxf(gcnt[g], 1.f);
        out[g] = d / cnt + blin[0];
    }
}

// ---------------- driver ----------------
extern "C" void kernel_launch(void* const* d_in, const int* in_sizes, int n_in,
                              void* d_out, int out_size, void* d_ws, size_t ws_size,
                              hipStream_t stream) {
    const float* x     = (const float*)d_in[0];
    const int*   ei    = (const int*)d_in[1];
    const int*   batch = (const int*)d_in[2];
    const float* Wl1   = (const float*)d_in[3];
    const float* bl1   = (const float*)d_in[4];
    const float* Wr1   = (const float*)d_in[5];
    const float* br1   = (const float*)d_in[6];
    const float* att1  = (const float*)d_in[7];
    const float* bias1 = (const float*)d_in[8];
    const float* Wl2   = (const float*)d_in[9];
    const float* bl2   = (const float*)d_in[10];
    const float* Wr2   = (const float*)d_in[11];
    const float* br2   = (const float*)d_in[12];
    const float* att2  = (const float*)d_in[13];
    const float* bias2 = (const float*)d_in[14];
    const float* Wlin  = (const float*)d_in[15];
    const float* blin  = (const float*)d_in[16];

    const int N   = in_sizes[2];
    const int E   = in_sizes[1] / 2;
    const int Fin = in_sizes[0] / N;     // 256
    const int G   = out_size;            // 64
    (void)n_in; (void)ws_size;

    char* p = (char*)d_ws;
    auto alloc = [&](size_t bytes) -> char* {
        char* r = p;
        p += (bytes + 255) & ~(size_t)255;
        return r;
    };
    float*    xlr   = (float*)alloc((size_t)N * 256 * 4);
    float*    hb    = (float*)alloc((size_t)N * 128 * 4);
    float*    wt    = (float*)alloc((size_t)Fin * 256 * 4);
    uint32_t* xlh   = (uint32_t*)alloc((size_t)N * 64 * 4);
    float*    dl    = (float*)alloc((size_t)N * 4 * 4);
    float*    dr    = (float*)alloc((size_t)N * 4 * 4);
    int*      cnt   = (int*)alloc((size_t)N * 4);
    int*      rowptr= (int*)alloc((size_t)(N + 1) * 4);
    int*      bsums = (int*)alloc(256 * 4);
    int*      boff  = (int*)alloc(256 * 4);
    int*      csr   = (int*)alloc((size_t)(E + N) * 4);
    float*    pool  = (float*)alloc((size_t)G * 128 * 4);
    float*    gcnt  = (float*)alloc((size_t)G * 4);

    const int NB1 = (E + EPB - 1) / EPB;           // partition blocks
    int*      g_hist = (int*)alloc((size_t)NB1 * NBKT * 4);
    int*      g_base = (int*)alloc((size_t)NB1 * NBKT * 4);
    // tmp (E u32) aliases xlr: CSR build completes before GEMM writes xlr.
    uint32_t* tmp = (uint32_t*)xlr;

    const int nb = (N + 255) / 256;
    const int eb = (E + 255) / 256;
    const int wb = (N + 3) / 4;

    // ---- rowptr (degree incl. self-loop) ----
    k_init_cnt<<<nb, 256, 0, stream>>>(cnt, N);
    k_count<<<eb, 256, 0, stream>>>(ei + E, cnt, E);
    k_scan_block<<<nb, 256, 0, stream>>>(cnt, rowptr, bsums, N);
    k_scan_top<<<1, 256, 0, stream>>>(bsums, boff, nb, rowptr, N);
    k_scan_add<<<nb, 256, 0, stream>>>(rowptr, boff, N);
    // ---- radix partition by dst bucket, then locality-friendly place ----
    k_hist<<<NB1, 256, 0, stream>>>(ei + E, g_hist, E);
    k_part_scan<<<1, 512, 0, stream>>>(g_hist, g_base, NB1);
    k_scatter<<<NB1, 256, 0, stream>>>(ei, g_base, tmp, E);
    k_init_cnt<<<nb, 256, 0, stream>>>(cnt, N);   // fill=1 (slot 0 = self)
    k_csr_self<<<nb, 256, 0, stream>>>(rowptr, csr, N);
    {
        const int PB = 128;
        const int chunk = (E + PB - 1) / PB;
        k_csr_place<<<PB, 256, 0, stream>>>(tmp, cnt, rowptr, csr, E, chunk);
    }

    // ---- layer 1 ----
    k_transpose_pair<<<(128 * Fin + 255) / 256, 256, 0, stream>>>(Wl1, Wr1, wt, Fin);
    k_gemm2<256><<<(N + 31) / 32, 256, 0, stream>>>(x, wt, bl1, br1, xlr, N);
    k_prep<<<wb, 256, 0, stream>>>(xlr, att1, xlh, dl, dr, N);
    k_gat_edge<<<wb, 256, 0, stream>>>(xlr, xlh, dl, dr, att1, bias1, rowptr, csr, hb, N, 1);

    // ---- layer 2 ----
    k_transpose_pair<<<(128 * 128 + 255) / 256, 256, 0, stream>>>(Wl2, Wr2, wt, 128);
    k_gemm2<128><<<(N + 31) / 32, 256, 0, stream>>>(hb, wt, bl2, br2, xlr, N);
    k_prep<<<wb, 256, 0, stream>>>(xlr, att2, xlh, dl, dr, N);
    k_gat_edge<<<wb, 256, 0, stream>>>(xlr, xlh, dl, dr, att2, bias2, rowptr, csr, hb, N, 0);

    // ---- pool + head ----
    k_zero<<<(G * 128 + 255) / 256, 256, 0, stream>>>(pool, G * 128);
    k_zero<<<1, 64, 0, stream>>>(gcnt, G);
    k_pool<<<(N + 31) / 32, 128, 0, stream>>>(hb, batch, pool, gcnt, N);
    k_head<<<G, 64, 0, stream>>>(pool, gcnt, Wlin, blin, (float*)d_out, G);
}

// Round 7
// 444.207 us; speedup vs baseline: 1.8474x; 1.1590x over previous
//
#include <hip/hip_runtime.h>
#include <hip/hip_fp16.h>
#include <math.h>
#include <stdint.h>

#define NEG_SLOPE 0.2f
#define EPB 4096          // edges per block in partition kernels
#define NBKT 128          // bucket space (dst>>9; 98 used for N=50000)

typedef _Float16 f16x8 __attribute__((ext_vector_type(8)));
typedef float f32x4 __attribute__((ext_vector_type(4)));

// ---------- DPP helpers: sum within each 16-lane row (zero DS ops) ----------
template<int CTRL>
__device__ __forceinline__ float dpp_add(float x) {
    union { float f; int i; } u, v;
    u.f = x;
    v.i = __builtin_amdgcn_update_dpp(0, u.i, CTRL, 0xF, 0xF, true);
    return x + v.f;
}
__device__ __forceinline__ float reduce16(float x) {
    x = dpp_add<0xB1>(x);   // quad_perm xor1
    x = dpp_add<0x4E>(x);   // quad_perm xor2
    x = dpp_add<0x124>(x);  // row_ror:4
    x = dpp_add<0x128>(x);  // row_ror:8
    return x;
}

// ---------- fp32 -> fp16 bulk convert (vectorized, coalesced) ----------
__global__ void k_f2h(const float* __restrict__ in, _Float16* __restrict__ out, int n4) {
    int i = blockIdx.x * 256 + threadIdx.x;
    if (i < n4) {
        float4 v = reinterpret_cast<const float4*>(in)[i];
        union { _Float16 h[4]; uint2 u; } o;
        o.h[0] = (_Float16)v.x; o.h[1] = (_Float16)v.y;
        o.h[2] = (_Float16)v.z; o.h[3] = (_Float16)v.w;
        reinterpret_cast<uint2*>(out)[i] = o.u;
    }
}

// ---------- pack W (Wl|Wr, [c][k] row-major = B^T) into MFMA B-frag order ----
// Wp[((kt*16+ct)*64 + l)*8 + e] = W[col=ct*16+(l&15)][k=kt*32+(l>>4)*8+e]
__global__ void k_wpack(const float* __restrict__ Wl, const float* __restrict__ Wr,
                        _Float16* __restrict__ Wp, int K) {
    int t = blockIdx.x * 256 + threadIdx.x;
    int total = (K / 32) * 16 * 64;
    if (t >= total) return;
    int l = t & 63, ct = (t >> 6) & 15, kt = t >> 10;
    int col = ct * 16 + (l & 15);
    int k0 = kt * 32 + (l >> 4) * 8;
    const float* src = (col < 128) ? (Wl + (size_t)col * K + k0)
                                   : (Wr + (size_t)(col - 128) * K + k0);
    union { _Float16 h[8]; uint4 u; } o;
#pragma unroll
    for (int e = 0; e < 8; ++e) o.h[e] = (_Float16)src[e];
    reinterpret_cast<uint4*>(Wp)[t] = o.u;
}

// ---------- MFMA GEMM: Y[n][0:256] = Xh @ [Wl|Wr]^T + [bl|br] ----------
// BM=32 rows/block, 4 waves x 4 col-tiles(16) each, K-tiles of 32.
template<int K>
__global__ __launch_bounds__(256) void k_gemm_mfma(
    const _Float16* __restrict__ Xh, const _Float16* __restrict__ Wp,
    const float* __restrict__ bl, const float* __restrict__ br,
    float* __restrict__ Y, int N) {
    __shared__ _Float16 xs[32 * K];
    const int t = threadIdx.x;
    const int w = t >> 6, l = t & 63;
    const int row0 = blockIdx.x * 32;
    constexpr int CPR = K / 8;                 // 16B chunks per row
    for (int cid = t; cid < 32 * CPR; cid += 256) {
        int r = cid / CPR, kc = cid % CPR;
        int gr = row0 + r;
        uint4 v = make_uint4(0u, 0u, 0u, 0u);
        if (gr < N) v = *reinterpret_cast<const uint4*>(Xh + (size_t)gr * K + kc * 8);
        int ba = (r * K * 2 + kc * 16) ^ ((r & 7) << 4);   // swizzle vs 16-way conflict
        *reinterpret_cast<uint4*>(reinterpret_cast<char*>(xs) + ba) = v;
    }
    __syncthreads();
    f32x4 acc[2][4];
#pragma unroll
    for (int m = 0; m < 2; ++m)
#pragma unroll
        for (int n = 0; n < 4; ++n) acc[m][n] = (f32x4){0.f, 0.f, 0.f, 0.f};
#pragma unroll
    for (int kt = 0; kt < K / 32; ++kt) {
        f16x8 a[2], b[4];
#pragma unroll
        for (int m = 0; m < 2; ++m) {
            int r = m * 16 + (l & 15);
            int ba = (r * K * 2 + kt * 64 + (l >> 4) * 16) ^ ((r & 7) << 4);
            a[m] = *reinterpret_cast<const f16x8*>(reinterpret_cast<const char*>(xs) + ba);
        }
#pragma unroll
        for (int n = 0; n < 4; ++n) {
            int ct = w * 4 + n;
            b[n] = *reinterpret_cast<const f16x8*>(Wp + ((size_t)(kt * 16 + ct) * 64 + l) * 8);
        }
#pragma unroll
        for (int m = 0; m < 2; ++m)
#pragma unroll
            for (int n = 0; n < 4; ++n)
                acc[m][n] = __builtin_amdgcn_mfma_f32_16x16x32_f16(a[m], b[n], acc[m][n], 0, 0, 0);
    }
#pragma unroll
    for (int n = 0; n < 4; ++n) {
        int col = (w * 4 + n) * 16 + (l & 15);
        float bv = (col < 128) ? bl[col] : br[col - 128];
#pragma unroll
        for (int m = 0; m < 2; ++m)
#pragma unroll
            for (int r4 = 0; r4 < 4; ++r4) {
                int gr = row0 + m * 16 + (l >> 4) * 4 + r4;
                if (gr < N) Y[(size_t)gr * 256 + col] = acc[m][n][r4] + bv;
            }
    }
}

// ---------------- CSR build: degree + rowptr ----------------
__global__ void k_init_cnt(int* __restrict__ cnt, int N) {
    int i = blockIdx.x * 256 + threadIdx.x;
    if (i < N) cnt[i] = 1;
}
__global__ void k_count(const int* __restrict__ dstArr, int* __restrict__ cnt, int E) {
    int e = blockIdx.x * 256 + threadIdx.x;
    if (e < E) atomicAdd(&cnt[dstArr[e]], 1);
}
__global__ void k_scan_block(const int* __restrict__ v_in, int* __restrict__ excl,
                             int* __restrict__ bsums, int N) {
    __shared__ int sh[256];
    int tid = threadIdx.x;
    int i = blockIdx.x * 256 + tid;
    int v = (i < N) ? v_in[i] : 0;
    sh[tid] = v;
    __syncthreads();
    for (int off = 1; off < 256; off <<= 1) {
        int add = (tid >= off) ? sh[tid - off] : 0;
        __syncthreads();
        sh[tid] += add;
        __syncthreads();
    }
    if (i < N) excl[i] = sh[tid] - v;
    if (tid == 255) bsums[blockIdx.x] = sh[255];
}
__global__ void k_scan_top(const int* __restrict__ bsums, int* __restrict__ boff,
                           int nb, int* __restrict__ rowptr, int N) {
    __shared__ int sh[256];
    int tid = threadIdx.x;
    int v = (tid < nb) ? bsums[tid] : 0;
    sh[tid] = v;
    __syncthreads();
    for (int off = 1; off < 256; off <<= 1) {
        int add = (tid >= off) ? sh[tid - off] : 0;
        __syncthreads();
        sh[tid] += add;
        __syncthreads();
    }
    if (tid < nb) boff[tid] = sh[tid] - v;
    if (tid == 255) rowptr[N] = sh[255];
}
__global__ void k_scan_add(int* __restrict__ rowptr, const int* __restrict__ boff, int N) {
    int i = blockIdx.x * 256 + threadIdx.x;
    if (i < N) rowptr[i] += boff[blockIdx.x];
}
__global__ void k_csr_self(const int* __restrict__ rowptr, int* __restrict__ csr, int N) {
    int i = blockIdx.x * 256 + threadIdx.x;
    if (i < N) csr[rowptr[i]] = i;
}

// ---------------- radix partition by dst>>9 (scan-based, no global RMW) ----
__global__ __launch_bounds__(256) void k_hist(const int* __restrict__ dstArr,
                                              int* __restrict__ g_hist, int E) {
    __shared__ int h[NBKT];
    int t = threadIdx.x;
    if (t < NBKT) h[t] = 0;
    __syncthreads();
    int s0 = blockIdx.x * EPB, s1 = min(E, s0 + EPB);
    for (int i = s0 + t; i < s1; i += 256) atomicAdd(&h[dstArr[i] >> 9], 1);
    __syncthreads();
    if (t < NBKT) g_hist[blockIdx.x * NBKT + t] = h[t];
}
__global__ __launch_bounds__(512) void k_part_scan(const int* __restrict__ g_hist,
                                                   int* __restrict__ g_base, int NB1) {
    __shared__ int csum[4][NBKT];
    __shared__ int btot[NBKT];
    __shared__ int bstart[NBKT];
    int tid = threadIdx.x, c = tid >> 7, b = tid & (NBKT - 1);
    int chunk = (NB1 + 3) >> 2;
    int i0 = c * chunk, i1 = min(NB1, i0 + chunk);
    int run = 0;
#pragma unroll 4
    for (int i = i0; i < i1; ++i) run += g_hist[i * NBKT + b];
    csum[c][b] = run;
    __syncthreads();
    int mytot = 0;
    if (c == 0) {
        mytot = csum[0][b] + csum[1][b] + csum[2][b] + csum[3][b];
        btot[b] = mytot;
    }
    __syncthreads();
    for (int off = 1; off < NBKT; off <<= 1) {
        int add = 0;
        if (c == 0 && b >= off) add = btot[b - off];
        __syncthreads();
        if (c == 0) btot[b] += add;
        __syncthreads();
    }
    if (c == 0) bstart[b] = btot[b] - mytot;  // exclusive
    __syncthreads();
    int base = bstart[b];
    for (int cc = 0; cc < c; ++cc) base += csum[cc][b];
    run = base;
#pragma unroll 4
    for (int i = i0; i < i1; ++i) {
        g_base[i * NBKT + b] = run;
        run += g_hist[i * NBKT + b];
    }
}
__global__ __launch_bounds__(256) void k_scatter(const int* __restrict__ ei,
                                                 const int* __restrict__ g_base,
                                                 uint32_t* __restrict__ tmp, int E) {
    __shared__ int off[NBKT];
    int t = threadIdx.x;
    if (t < NBKT) off[t] = g_base[blockIdx.x * NBKT + t];
    __syncthreads();
    int s0 = blockIdx.x * EPB, s1 = min(E, s0 + EPB);
    for (int i = s0 + t; i < s1; i += 256) {
        int s = ei[i], d = ei[E + i];
        int pos = atomicAdd(&off[d >> 9], 1);
        tmp[pos] = ((uint32_t)s << 16) | (uint32_t)d;
    }
}
__global__ __launch_bounds__(256) void k_csr_place(const uint32_t* __restrict__ tmp,
                                                   int* __restrict__ fill,
                                                   const int* __restrict__ rowptr,
                                                   int* __restrict__ csr, int E, int chunk) {
    int s0 = blockIdx.x * chunk, s1 = min(E, s0 + chunk);
    for (int i = s0 + threadIdx.x; i < s1; i += 256) {
        uint32_t pk = tmp[i];
        int src = (int)(pk >> 16);
        int d   = (int)(pk & 0xFFFFu);
        int slot = atomicAdd(&fill[d], 1);
        csr[rowptr[d] + slot] = src;
    }
}

// ---------------- prep: fp16-pack xl + per-head linear att dots ------------
__global__ __launch_bounds__(256) void k_prep(
    const float* __restrict__ xlr, const float* __restrict__ att,
    uint32_t* __restrict__ xlh, float* __restrict__ dl, float* __restrict__ dr,
    int N) {
    int wid = threadIdx.x >> 6, lane = threadIdx.x & 63;
    int n = blockIdx.x * 4 + wid;
    if (n >= N) return;
    int h = lane >> 4, j = lane & 15;
    int c0 = h * 32 + j, c1 = c0 + 16;
    const float* row = xlr + (size_t)n * 256;
    float xl0 = row[c0], xl1 = row[c1];
    float xr0 = row[128 + c0], xr1 = row[128 + c1];
    float a0 = att[c0], a1 = att[c1];
    __half2 hp = __floats2half2_rn(xl0, xl1);
    xlh[(size_t)n * 64 + lane] = *reinterpret_cast<uint32_t*>(&hp);
    float pl = reduce16(fmaf(a0, xl0, a1 * xl1));
    float pr = reduce16(fmaf(a0, xr0, a1 * xr1));
    if (j == 0) {
        dl[n * 4 + h] = 0.6f * pl;
        dr[n * 4 + h] = 0.6f * pr;
    }
}

// ---------------- fused GATv2 edge kernel ----------------
__global__ __launch_bounds__(256) void k_gat_edge(
    const float* __restrict__ xlr, const uint32_t* __restrict__ xlh,
    const float* __restrict__ dl, const float* __restrict__ dr,
    const float* __restrict__ att, const float* __restrict__ bias,
    const int* __restrict__ rowptr, const int* __restrict__ csr,
    float* __restrict__ out, int N, int relu_flag) {
    int wid = threadIdx.x >> 6;
    int lane = threadIdx.x & 63;
    int n = blockIdx.x * 4 + wid;
    if (n >= N) return;
    const int h = lane >> 4, j = lane & 15;
    const int c0 = h * 32 + j, c1 = c0 + 16;
    float xr0 = xlr[(size_t)n * 256 + 128 + c0];
    float xr1 = xlr[(size_t)n * 256 + 128 + c1];
    float a0 = att[c0], a1 = att[c1];
    float drh = dr[n * 4 + h];
    float ssum = 0.f, acc0 = 0.f, acc1 = 0.f;
    int beg = rowptr[n], end = rowptr[n + 1];
    int i = beg;
    for (; i + 3 < end; i += 4) {
        int s[4];
#pragma unroll
        for (int e = 0; e < 4; ++e) s[e] = csr[i + e];
        uint32_t q[4];
        float dv[4];
#pragma unroll
        for (int e = 0; e < 4; ++e) {
            q[e] = xlh[(size_t)s[e] * 64 + lane];
            dv[e] = dl[s[e] * 4 + h] + drh;
        }
#pragma unroll
        for (int e = 0; e < 4; ++e) {
            __half2 hv = *reinterpret_cast<__half2*>(&q[e]);
            float A0 = __low2float(hv), A1 = __high2float(hv);
            float p = fmaf(a0, fabsf(A0 + xr0), a1 * fabsf(A1 + xr1));
            p = reduce16(p);
            float alpha = fmaf(0.4f, p, dv[e]);
            float w = __expf(alpha);
            ssum += w;
            acc0 = fmaf(w, A0, acc0);
            acc1 = fmaf(w, A1, acc1);
        }
    }
    for (; i < end; ++i) {
        int sA = csr[i];
        uint32_t qA = xlh[(size_t)sA * 64 + lane];
        float dA = dl[sA * 4 + h] + drh;
        __half2 hv = *reinterpret_cast<__half2*>(&qA);
        float A0 = __low2float(hv), A1 = __high2float(hv);
        float p = fmaf(a0, fabsf(A0 + xr0), a1 * fabsf(A1 + xr1));
        p = reduce16(p);
        float alpha = fmaf(0.4f, p, dA);
        float w = __expf(alpha);
        ssum += w;
        acc0 = fmaf(w, A0, acc0);
        acc1 = fmaf(w, A1, acc1);
    }
    float inv = 1.f / (ssum + 1e-16f);
    float o0 = acc0 * inv + bias[c0];
    float o1 = acc1 * inv + bias[c1];
    if (relu_flag) { o0 = fmaxf(o0, 0.f); o1 = fmaxf(o1, 0.f); }
    out[(size_t)n * 128 + c0] = o0;
    out[(size_t)n * 128 + c1] = o1;
}

// ---------------- pooling ----------------
__global__ void k_zero(float* __restrict__ p, int n) {
    int i = blockIdx.x * 256 + threadIdx.x;
    if (i < n) p[i] = 0.f;
}
__global__ __launch_bounds__(128) void k_pool(
    const float* __restrict__ h, const int* __restrict__ batch,
    float* __restrict__ pool, float* __restrict__ gcnt, int N) {
    const int NPB = 32;
    int c = threadIdx.x;
    int n0 = blockIdx.x * NPB;
    int n1 = min(n0 + NPB, N);
    float acc = 0.f;
    int curg = -1, cntl = 0;
    for (int n = n0; n < n1; ++n) {
        int g = batch[n];
        if (g != curg) {
            if (curg >= 0) {
                atomicAdd(&pool[curg * 128 + c], acc);
                if (c == 0) atomicAdd(&gcnt[curg], (float)cntl);
            }
            acc = 0.f; cntl = 0; curg = g;
        }
        acc += h[(size_t)n * 128 + c];
        cntl++;
    }
    if (curg >= 0) {
        atomicAdd(&pool[curg * 128 + c], acc);
        if (c == 0) atomicAdd(&gcnt[curg], (float)cntl);
    }
}
__global__ __launch_bounds__(64) void k_head(
    const float* __restrict__ pool, const float* __restrict__ gcnt,
    const float* __restrict__ Wlin, const float* __restrict__ blin,
    float* __restrict__ out, int G) {
    int g = blockIdx.x, l = threadIdx.x;
    float d = pool[g * 128 + l] * Wlin[l] + pool[g * 128 + l + 64] * Wlin[l + 64];
#pragma unroll
    for (int off = 32; off; off >>= 1) d += __shfl_xor(d, off, 64);
    if (l == 0) {
        float cnt = fmaxf(gcnt[g], 1.f);
        out[g] = d / cnt + blin[0];
    }
}

// ---------------- driver ----------------
extern "C" void kernel_launch(void* const* d_in, const int* in_sizes, int n_in,
                              void* d_out, int out_size, void* d_ws, size_t ws_size,
                              hipStream_t stream) {
    const float* x     = (const float*)d_in[0];
    const int*   ei    = (const int*)d_in[1];
    const int*   batch = (const int*)d_in[2];
    const float* Wl1   = (const float*)d_in[3];
    const float* bl1   = (const float*)d_in[4];
    const float* Wr1   = (const float*)d_in[5];
    const float* br1   = (const float*)d_in[6];
    const float* att1  = (const float*)d_in[7];
    const float* bias1 = (const float*)d_in[8];
    const float* Wl2   = (const float*)d_in[9];
    const float* bl2   = (const float*)d_in[10];
    const float* Wr2   = (const float*)d_in[11];
    const float* br2   = (const float*)d_in[12];
    const float* att2  = (const float*)d_in[13];
    const float* bias2 = (const float*)d_in[14];
    const float* Wlin  = (const float*)d_in[15];
    const float* blin  = (const float*)d_in[16];

    const int N   = in_sizes[2];
    const int E   = in_sizes[1] / 2;
    const int Fin = in_sizes[0] / N;     // 256
    const int G   = out_size;            // 64
    (void)n_in; (void)ws_size;

    char* p = (char*)d_ws;
    auto alloc = [&](size_t bytes) -> char* {
        char* r = p;
        p += (bytes + 255) & ~(size_t)255;
        return r;
    };
    float*    xlr   = (float*)alloc((size_t)N * 256 * 4);
    float*    hb    = (float*)alloc((size_t)N * 128 * 4);   // also aliases Xh (fp16 N*256)
    float*    wt    = (float*)alloc((size_t)Fin * 256 * 4); // holds Wp (fp16 K*256)
    uint32_t* xlh   = (uint32_t*)alloc((size_t)N * 64 * 4); // also aliases hbh (fp16 N*128)
    float*    dl    = (float*)alloc((size_t)N * 4 * 4);
    float*    dr    = (float*)alloc((size_t)N * 4 * 4);
    int*      cnt   = (int*)alloc((size_t)N * 4);
    int*      rowptr= (int*)alloc((size_t)(N + 1) * 4);
    int*      bsums = (int*)alloc(256 * 4);
    int*      boff  = (int*)alloc(256 * 4);
    int*      csr   = (int*)alloc((size_t)(E + N) * 4);
    float*    pool  = (float*)alloc((size_t)G * 128 * 4);
    float*    gcnt  = (float*)alloc((size_t)G * 4);

    const int NB1 = (E + EPB - 1) / EPB;           // partition blocks
    int*      g_hist = (int*)alloc((size_t)NB1 * NBKT * 4);
    int*      g_base = (int*)alloc((size_t)NB1 * NBKT * 4);
    // tmp (E u32) aliases xlr: CSR build completes before GEMM writes xlr.
    uint32_t* tmp = (uint32_t*)xlr;
    _Float16* Xh  = (_Float16*)hb;    // live: before edge1 writes hb
    _Float16* hbh = (_Float16*)xlh;   // live: after edge1, dead before prep2 writes xlh
    _Float16* Wp  = (_Float16*)wt;

    const int nb = (N + 255) / 256;
    const int eb = (E + 255) / 256;
    const int wb = (N + 3) / 4;
    const int gb = (N + 31) / 32;

    // ---- rowptr (degree incl. self-loop) ----
    k_init_cnt<<<nb, 256, 0, stream>>>(cnt, N);
    k_count<<<eb, 256, 0, stream>>>(ei + E, cnt, E);
    k_scan_block<<<nb, 256, 0, stream>>>(cnt, rowptr, bsums, N);
    k_scan_top<<<1, 256, 0, stream>>>(bsums, boff, nb, rowptr, N);
    k_scan_add<<<nb, 256, 0, stream>>>(rowptr, boff, N);
    // ---- radix partition by dst bucket, then locality-friendly place ----
    k_hist<<<NB1, 256, 0, stream>>>(ei + E, g_hist, E);
    k_part_scan<<<1, 512, 0, stream>>>(g_hist, g_base, NB1);
    k_scatter<<<NB1, 256, 0, stream>>>(ei, g_base, tmp, E);
    k_init_cnt<<<nb, 256, 0, stream>>>(cnt, N);   // fill=1 (slot 0 = self)
    k_csr_self<<<nb, 256, 0, stream>>>(rowptr, csr, N);
    {
        const int PB = 128;
        const int chunk = (E + PB - 1) / PB;
        k_csr_place<<<PB, 256, 0, stream>>>(tmp, cnt, rowptr, csr, E, chunk);
    }

    // ---- layer 1 (K=256 MFMA fp16) ----
    k_f2h<<<(N * Fin / 4 + 255) / 256, 256, 0, stream>>>(x, Xh, N * Fin / 4);
    k_wpack<<<((Fin / 32) * 16 * 64 + 255) / 256, 256, 0, stream>>>(Wl1, Wr1, Wp, Fin);
    k_gemm_mfma<256><<<gb, 256, 0, stream>>>(Xh, Wp, bl1, br1, xlr, N);
    k_prep<<<wb, 256, 0, stream>>>(xlr, att1, xlh, dl, dr, N);
    k_gat_edge<<<wb, 256, 0, stream>>>(xlr, xlh, dl, dr, att1, bias1, rowptr, csr, hb, N, 1);

    // ---- layer 2 (K=128 MFMA fp16) ----
    k_f2h<<<(N * 128 / 4 + 255) / 256, 256, 0, stream>>>(hb, hbh, N * 128 / 4);
    k_wpack<<<((128 / 32) * 16 * 64 + 255) / 256, 256, 0, stream>>>(Wl2, Wr2, Wp, 128);
    k_gemm_mfma<128><<<gb, 256, 0, stream>>>(hbh, Wp, bl2, br2, xlr, N);
    k_prep<<<wb, 256, 0, stream>>>(xlr, att2, xlh, dl, dr, N);
    k_gat_edge<<<wb, 256, 0, stream>>>(xlr, xlh, dl, dr, att2, bias2, rowptr, csr, hb, N, 0);

    // ---- pool + head ----
    k_zero<<<(G * 128 + 255) / 256, 256, 0, stream>>>(pool, G * 128);
    k_zero<<<1, 64, 0, stream>>>(gcnt, G);
    k_pool<<<(N + 31) / 32, 128, 0, stream>>>(hb, batch, pool, gcnt, N);
    k_head<<<G, 64, 0, stream>>>(pool, gcnt, Wlin, blin, (float*)d_out, G);
}

// Round 10
// 323.911 us; speedup vs baseline: 2.5335x; 1.3714x over previous
//
#include <hip/hip_runtime.h>
#include <hip/hip_fp16.h>
#include <math.h>
#include <stdint.h>

#define EPB 4096          // edges per block in partition kernels
#define NBKT 128          // dst>>9 buckets (98 used for N=50000)

typedef _Float16 f16x8 __attribute__((ext_vector_type(8)));
typedef float f32x4 __attribute__((ext_vector_type(4)));
typedef _Float16 h2 __attribute__((ext_vector_type(2)));

// ---------- 16-lane row sum via DPP (builtin: compiler handles hazards &
// fuses mov_dpp+add into v_add_f32_dpp) ----------
template<int CTRL>
__device__ __forceinline__ float dpp_add(float x) {
    union { float f; int i; } u, v;
    u.f = x;
    v.i = __builtin_amdgcn_update_dpp(0, u.i, CTRL, 0xF, 0xF, true);
    return x + v.f;
}
__device__ __forceinline__ float reduce16(float x) {
    x = dpp_add<0xB1>(x);   // quad_perm xor1
    x = dpp_add<0x4E>(x);   // quad_perm xor2
    x = dpp_add<0x124>(x);  // row_ror:4
    x = dpp_add<0x128>(x);  // row_ror:8
    return x;               // all 16 lanes of the row hold the row sum
}

// ---------- pack W (Wl|Wr, [c][k] row-major = B^T) into MFMA B-frag order ----
__global__ void k_wpack(const float* __restrict__ Wl, const float* __restrict__ Wr,
                        _Float16* __restrict__ Wp, int K) {
    int t = blockIdx.x * 256 + threadIdx.x;
    int total = (K / 32) * 16 * 64;
    if (t >= total) return;
    int l = t & 63, ct = (t >> 6) & 15, kt = t >> 10;
    int col = ct * 16 + (l & 15);
    int k0 = kt * 32 + (l >> 4) * 8;
    const float* src = (col < 128) ? (Wl + (size_t)col * K + k0)
                                   : (Wr + (size_t)(col - 128) * K + k0);
    union { _Float16 h[8]; uint4 u; } o;
#pragma unroll
    for (int e = 0; e < 8; ++e) o.h[e] = (_Float16)src[e];
    reinterpret_cast<uint4*>(Wp)[t] = o.u;
}

// ---------- MFMA GEMM: Y[n][0:256] = X @ [Wl|Wr]^T + [bl|br] ----------
// CVT=1: X is fp32, converted during LDS staging. CVT=0: X fp16.
template<int K, int CVT>
__global__ __launch_bounds__(256) void k_gemm_mfma(
    const void* __restrict__ Xin, const _Float16* __restrict__ Wp,
    const float* __restrict__ bl, const float* __restrict__ br,
    float* __restrict__ Y, int N) {
    __shared__ _Float16 xs[32 * K];
    const int t = threadIdx.x, w = t >> 6, l = t & 63;
    const int row0 = blockIdx.x * 32;
    if (CVT) {
        const float* X = (const float*)Xin;
        for (int cid = t; cid < 32 * (K / 4); cid += 256) {
            int r = cid / (K / 4), c4 = (cid % (K / 4)) * 4;
            int gr = row0 + r;
            float4 v = make_float4(0.f, 0.f, 0.f, 0.f);
            if (gr < N) v = *reinterpret_cast<const float4*>(X + (size_t)gr * K + c4);
            h2 lo = {(_Float16)v.x, (_Float16)v.y};
            h2 hi = {(_Float16)v.z, (_Float16)v.w};
            uint2 pk;
            pk.x = __builtin_bit_cast(uint32_t, lo);
            pk.y = __builtin_bit_cast(uint32_t, hi);
            int ba = (r * K * 2 + c4 * 2) ^ ((r & 7) << 4);
            *reinterpret_cast<uint2*>(reinterpret_cast<char*>(xs) + ba) = pk;
        }
    } else {
        const _Float16* X = (const _Float16*)Xin;
        for (int cid = t; cid < 32 * (K / 8); cid += 256) {
            int r = cid / (K / 8), c8 = (cid % (K / 8)) * 8;
            int gr = row0 + r;
            uint4 v = make_uint4(0u, 0u, 0u, 0u);
            if (gr < N) v = *reinterpret_cast<const uint4*>(X + (size_t)gr * K + c8);
            int ba = (r * K * 2 + c8 * 2) ^ ((r & 7) << 4);
            *reinterpret_cast<uint4*>(reinterpret_cast<char*>(xs) + ba) = v;
        }
    }
    __syncthreads();
    f32x4 acc[2][4];
#pragma unroll
    for (int m = 0; m < 2; ++m)
#pragma unroll
        for (int n = 0; n < 4; ++n) acc[m][n] = (f32x4){0.f, 0.f, 0.f, 0.f};
#pragma unroll
    for (int kt = 0; kt < K / 32; ++kt) {
        f16x8 a[2], b[4];
#pragma unroll
        for (int m = 0; m < 2; ++m) {
            int r = m * 16 + (l & 15);
            int ba = (r * K * 2 + kt * 64 + (l >> 4) * 16) ^ ((r & 7) << 4);
            a[m] = *reinterpret_cast<const f16x8*>(reinterpret_cast<const char*>(xs) + ba);
        }
#pragma unroll
        for (int n = 0; n < 4; ++n) {
            int ct = w * 4 + n;
            b[n] = *reinterpret_cast<const f16x8*>(Wp + ((size_t)(kt * 16 + ct) * 64 + l) * 8);
        }
#pragma unroll
        for (int m = 0; m < 2; ++m)
#pragma unroll
            for (int n = 0; n < 4; ++n)
                acc[m][n] = __builtin_amdgcn_mfma_f32_16x16x32_f16(a[m], b[n], acc[m][n], 0, 0, 0);
    }
#pragma unroll
    for (int n = 0; n < 4; ++n) {
        int col = (w * 4 + n) * 16 + (l & 15);
        float bv = (col < 128) ? bl[col] : br[col - 128];
#pragma unroll
        for (int m = 0; m < 2; ++m)
#pragma unroll
            for (int r4 = 0; r4 < 4; ++r4) {
                int gr = row0 + m * 16 + (l >> 4) * 4 + r4;
                if (gr < N) Y[(size_t)gr * 256 + col] = acc[m][n][r4] + bv;
            }
    }
}

// ---------------- radix partition by dst>>9 (scan-based, no global RMW) ----
__global__ __launch_bounds__(256) void k_hist(const int* __restrict__ dstArr,
                                              int* __restrict__ g_hist, int E) {
    __shared__ int h[NBKT];
    int t = threadIdx.x;
    if (t < NBKT) h[t] = 0;
    __syncthreads();
    int s0 = blockIdx.x * EPB, s1 = min(E, s0 + EPB);
    for (int i = s0 + t; i < s1; i += 256) atomicAdd(&h[dstArr[i] >> 9], 1);
    __syncthreads();
    if (t < NBKT) g_hist[blockIdx.x * NBKT + t] = h[t];
}
__global__ __launch_bounds__(512) void k_part_scan(const int* __restrict__ g_hist,
                                                   int* __restrict__ g_base,
                                                   int* __restrict__ bstart_out,
                                                   int NB1, int E) {
    __shared__ int csum[4][NBKT];
    __shared__ int btot[NBKT];
    __shared__ int bstart[NBKT];
    int tid = threadIdx.x, c = tid >> 7, b = tid & (NBKT - 1);
    int chunk = (NB1 + 3) >> 2;
    int i0 = c * chunk, i1 = min(NB1, i0 + chunk);
    int run = 0;
    for (int i = i0; i < i1; ++i) run += g_hist[i * NBKT + b];
    csum[c][b] = run;
    __syncthreads();
    int mytot = 0;
    if (c == 0) {
        mytot = csum[0][b] + csum[1][b] + csum[2][b] + csum[3][b];
        btot[b] = mytot;
    }
    __syncthreads();
    for (int off = 1; off < NBKT; off <<= 1) {
        int add = 0;
        if (c == 0 && b >= off) add = btot[b - off];
        __syncthreads();
        if (c == 0) btot[b] += add;
        __syncthreads();
    }
    if (c == 0) { bstart[b] = btot[b] - mytot; bstart_out[b] = bstart[b]; }
    if (tid == 0) bstart_out[NBKT] = E;
    __syncthreads();
    int base = bstart[b];
    for (int cc = 0; cc < c; ++cc) base += csum[cc][b];
    run = base;
    for (int i = i0; i < i1; ++i) {
        g_base[i * NBKT + b] = run;
        run += g_hist[i * NBKT + b];
    }
}
__global__ __launch_bounds__(256) void k_scatter(const int* __restrict__ ei,
                                                 const int* __restrict__ g_base,
                                                 uint32_t* __restrict__ tmp, int E) {
    __shared__ int off[NBKT];
    int t = threadIdx.x;
    if (t < NBKT) off[t] = g_base[blockIdx.x * NBKT + t];
    __syncthreads();
    int s0 = blockIdx.x * EPB, s1 = min(E, s0 + EPB);
    for (int i = s0 + t; i < s1; i += 256) {
        int s = ei[i], d = ei[E + i];
        int pos = atomicAdd(&off[d >> 9], 1);
        tmp[pos] = ((uint32_t)s << 16) | (uint32_t)d;
    }
}
// One block per 512-node bucket: LDS hist+scan -> rowptr, self-loops, and
// ordered edge placement, all within a ~67KB contiguous csr window.
__global__ __launch_bounds__(256) void k_bucket_csr(
    const uint32_t* __restrict__ tmp, const int* __restrict__ bstart,
    int* __restrict__ rowptr, int* __restrict__ csr, int N, int E) {
    __shared__ int cnt[512];
    __shared__ int fil[512];
    int b = blockIdx.x, t = threadIdx.x;
    int s0 = bstart[b], s1 = bstart[b + 1];
    cnt[t] = 0; cnt[t + 256] = 0;
    __syncthreads();
    for (int i = s0 + t; i < s1; i += 256)
        atomicAdd(&cnt[tmp[i] & 511], 1);
    __syncthreads();
    int c0 = cnt[t], c1 = cnt[t + 256];
    for (int off = 1; off < 512; off <<= 1) {
        int v0 = (t >= off) ? cnt[t - off] : 0;
        int v1 = (t + 256 >= off) ? cnt[t + 256 - off] : 0;
        __syncthreads();
        cnt[t] += v0; cnt[t + 256] += v1;
        __syncthreads();
    }
    int e0 = cnt[t] - c0, e1 = cnt[t + 256] - c1;   // exclusive
    __syncthreads();
    cnt[t] = e0; cnt[t + 256] = e1;
    fil[t] = 1; fil[t + 256] = 1;                   // slot 0 = self-loop
    __syncthreads();
    int n0 = b * 512;
#pragma unroll
    for (int k = 0; k < 2; ++k) {
        int ld = t + k * 256, n = n0 + ld;
        if (n < N) {
            int rp = s0 + cnt[ld] + n;              // edgesBefore + selfLoopsBefore
            rowptr[n] = rp;
            csr[rp] = n;
        }
    }
    if (b == 0 && t == 0) rowptr[N] = E + N;
    for (int i = s0 + t; i < s1; i += 256) {
        uint32_t pk = tmp[i];
        int d = (int)(pk & 0xFFFFu), ld = d & 511;
        int slot = atomicAdd(&fil[ld], 1);
        csr[s0 + cnt[ld] + d + slot] = (int)(pk >> 16);
    }
}

// ---------------- prep: plain-layout fp16 xl + edl = exp(0.6*att.xl) -------
__global__ __launch_bounds__(256) void k_prep(
    const float* __restrict__ xlr, const float* __restrict__ att,
    uint32_t* __restrict__ xlh, float* __restrict__ edl, int N) {
    int wid = threadIdx.x >> 6, l = threadIdx.x & 63;
    int n = blockIdx.x * 4 + wid;
    if (n >= N) return;
    float2 xv = *reinterpret_cast<const float2*>(xlr + (size_t)n * 256 + 2 * l);
    float2 av = *reinterpret_cast<const float2*>(att + 2 * l);
    h2 hp = {(_Float16)xv.x, (_Float16)xv.y};
    xlh[(size_t)n * 64 + l] = __builtin_bit_cast(uint32_t, hp);
    float pl = reduce16(fmaf(av.x, xv.x, av.y * xv.y));
    if ((l & 15) == 0) edl[n * 4 + (l >> 4)] = __expf(0.6f * pl);
}

// ---------------- fused GATv2 edge kernel: one wave per node ----------------
// w_e = edl[s] * exp( sum_head 0.4*att_c*|xl_c + xr_c| )   [fp32 alpha math]
// (exp(0.6*dotr_d) cancels in the softmax.)
template<int OUT16>
__global__ __launch_bounds__(256) void k_gat_edge(
    const float* __restrict__ xlr, const uint32_t* __restrict__ xlh,
    const float* __restrict__ edl,
    const float* __restrict__ att, const float* __restrict__ bias,
    const int* __restrict__ rowptr, const int* __restrict__ csr,
    void* __restrict__ out, int N) {
    int wid = threadIdx.x >> 6, l = threadIdx.x & 63;
    int n = blockIdx.x * 4 + wid;
    if (n >= N) return;
    float2 xrv = *reinterpret_cast<const float2*>(xlr + (size_t)n * 256 + 128 + 2 * l);
    float2 av  = *reinterpret_cast<const float2*>(att + 2 * l);
    const float xr0 = xrv.x, xr1 = xrv.y;
    const float a04 = av.x * 0.4f, a14 = av.y * 0.4f;
    const uint32_t l4 = (uint32_t)(l << 2);
    const uint32_t h4 = (uint32_t)((l >> 4) << 2);
    const char* xlhc = (const char*)xlh;
    const char* edlc = (const char*)edl;
    float ssum = 0.f, acc0 = 0.f, acc1 = 0.f;
    int beg = rowptr[n], end = rowptr[n + 1];
    int i = beg;
    for (; i + 3 < end; i += 4) {
        uint32_t q[4]; float ev[4];
#pragma unroll
        for (int e = 0; e < 4; ++e) {
            uint32_t s = (uint32_t)csr[i + e];
            q[e]  = *(const uint32_t*)(xlhc + ((s << 8) + l4));
            ev[e] = *(const float*)(edlc + ((s << 4) + h4));
        }
#pragma unroll
        for (int e = 0; e < 4; ++e) {
            h2 A = __builtin_bit_cast(h2, q[e]);
            float A0 = (float)A.x, A1 = (float)A.y;
            float t0 = A0 + xr0;
            float t1 = A1 + xr1;
            float p = fabsf(t0) * a04;
            p = fmaf(fabsf(t1), a14, p);
            p = reduce16(p);
            float wgt = ev[e] * __expf(p);
            ssum += wgt;
            acc0 = fmaf(wgt, A0, acc0);
            acc1 = fmaf(wgt, A1, acc1);
        }
    }
    for (; i < end; ++i) {
        uint32_t s = (uint32_t)csr[i];
        uint32_t q = *(const uint32_t*)(xlhc + ((s << 8) + l4));
        float ev   = *(const float*)(edlc + ((s << 4) + h4));
        h2 A = __builtin_bit_cast(h2, q);
        float A0 = (float)A.x, A1 = (float)A.y;
        float t0 = A0 + xr0;
        float t1 = A1 + xr1;
        float p = fabsf(t0) * a04;
        p = fmaf(fabsf(t1), a14, p);
        p = reduce16(p);
        float wgt = ev * __expf(p);
        ssum += wgt;
        acc0 = fmaf(wgt, A0, acc0);
        acc1 = fmaf(wgt, A1, acc1);
    }
    float inv = 1.f / ssum;
    float2 bv = *reinterpret_cast<const float2*>(bias + 2 * l);
    float o0 = fmaf(acc0, inv, bv.x);
    float o1 = fmaf(acc1, inv, bv.y);
    if (OUT16) {   // layer 1: relu + fp16 (feeds next GEMM directly)
        o0 = fmaxf(o0, 0.f); o1 = fmaxf(o1, 0.f);
        h2 oh = {(_Float16)o0, (_Float16)o1};
        ((uint32_t*)out)[(size_t)n * 64 + l] = __builtin_bit_cast(uint32_t, oh);
    } else {       // layer 2: fp32 for pooling
        ((float2*)out)[(size_t)n * 64 + l] = make_float2(o0, o1);
    }
}

// ---------------- pooling ----------------
__global__ void k_zero(float* __restrict__ p, int n) {
    int i = blockIdx.x * 256 + threadIdx.x;
    if (i < n) p[i] = 0.f;
}
__global__ __launch_bounds__(128) void k_pool(
    const float* __restrict__ h, const int* __restrict__ batch,
    float* __restrict__ pool, float* __restrict__ gcnt, int N) {
    const int NPB = 32;
    int c = threadIdx.x;
    int n0 = blockIdx.x * NPB;
    int n1 = min(n0 + NPB, N);
    float acc = 0.f;
    int curg = -1, cntl = 0;
    for (int n = n0; n < n1; ++n) {
        int g = batch[n];
        if (g != curg) {
            if (curg >= 0) {
                atomicAdd(&pool[curg * 128 + c], acc);
                if (c == 0) atomicAdd(&gcnt[curg], (float)cntl);
            }
            acc = 0.f; cntl = 0; curg = g;
        }
        acc += h[(size_t)n * 128 + c];
        cntl++;
    }
    if (curg >= 0) {
        atomicAdd(&pool[curg * 128 + c], acc);
        if (c == 0) atomicAdd(&gcnt[curg], (float)cntl);
    }
}
__global__ __launch_bounds__(64) void k_head(
    const float* __restrict__ pool, const float* __restrict__ gcnt,
    const float* __restrict__ Wlin, const float* __restrict__ blin,
    float* __restrict__ out, int G) {
    int g = blockIdx.x, l = threadIdx.x;
    float d = pool[g * 128 + l] * Wlin[l] + pool[g * 128 + l + 64] * Wlin[l + 64];
#pragma unroll
    for (int off = 32; off; off >>= 1) d += __shfl_xor(d, off, 64);
    if (l == 0) {
        float cnt = fmaxf(gcnt[g], 1.f);
        out[g] = d / cnt + blin[0];
    }
}

// ---------------- driver ----------------
extern "C" void kernel_launch(void* const* d_in, const int* in_sizes, int n_in,
                              void* d_out, int out_size, void* d_ws, size_t ws_size,
                              hipStream_t stream) {
    const float* x     = (const float*)d_in[0];
    const int*   ei    = (const int*)d_in[1];
    const int*   batch = (const int*)d_in[2];
    const float* Wl1   = (const float*)d_in[3];
    const float* bl1   = (const float*)d_in[4];
    const float* Wr1   = (const float*)d_in[5];
    const float* br1   = (const float*)d_in[6];
    const float* att1  = (const float*)d_in[7];
    const float* bias1 = (const float*)d_in[8];
    const float* Wl2   = (const float*)d_in[9];
    const float* bl2   = (const float*)d_in[10];
    const float* Wr2   = (const float*)d_in[11];
    const float* br2   = (const float*)d_in[12];
    const float* att2  = (const float*)d_in[13];
    const float* bias2 = (const float*)d_in[14];
    const float* Wlin  = (const float*)d_in[15];
    const float* blin  = (const float*)d_in[16];

    const int N   = in_sizes[2];
    const int E   = in_sizes[1] / 2;
    const int Fin = in_sizes[0] / N;     // 256
    const int G   = out_size;            // 64
    (void)n_in; (void)ws_size;

    char* p = (char*)d_ws;
    auto alloc = [&](size_t bytes) -> char* {
        char* r = p;
        p += (bytes + 255) & ~(size_t)255;
        return r;
    };
    float*    xlr   = (float*)alloc((size_t)N * 256 * 4);   // gemm out; aliases tmp
    float*    hb    = (float*)alloc((size_t)N * 128 * 4);   // layer2 fp32 out
    uint32_t* hbh   = (uint32_t*)alloc((size_t)N * 64 * 4); // layer1 fp16 out
    float*    wt    = (float*)alloc((size_t)Fin * 256 * 4); // Wp (fp16)
    uint32_t* xlh   = (uint32_t*)alloc((size_t)N * 64 * 4); // xl fp16 plain layout
    float*    edl   = (float*)alloc((size_t)N * 4 * 4);
    int*      rowptr= (int*)alloc((size_t)(N + 1) * 4);
    int*      csr   = (int*)alloc((size_t)(E + N) * 4);
    float*    poolg = (float*)alloc((size_t)G * 129 * 4);
    float*    pool  = poolg;
    float*    gcnt  = poolg + (size_t)G * 128;

    const int NB1 = (E + EPB - 1) / EPB;
    int*      g_hist = (int*)alloc((size_t)NB1 * NBKT * 4);
    int*      g_base = (int*)alloc((size_t)NB1 * NBKT * 4);
    int*      bstart = (int*)alloc((size_t)(NBKT + 1) * 4);
    uint32_t* tmp = (uint32_t*)xlr;   // CSR build finishes before gemm writes xlr
    _Float16* Wp  = (_Float16*)wt;

    const int wb = (N + 3) / 4;
    const int gb = (N + 31) / 32;

    // ---- CSR (bucketed radix partition + per-bucket build) ----
    k_hist<<<NB1, 256, 0, stream>>>(ei + E, g_hist, E);
    k_part_scan<<<1, 512, 0, stream>>>(g_hist, g_base, bstart, NB1, E);
    k_scatter<<<NB1, 256, 0, stream>>>(ei, g_base, tmp, E);
    k_bucket_csr<<<NBKT, 256, 0, stream>>>(tmp, bstart, rowptr, csr, N, E);

    // ---- layer 1 ----
    k_wpack<<<((Fin / 32) * 16 * 64 + 255) / 256, 256, 0, stream>>>(Wl1, Wr1, Wp, Fin);
    k_gemm_mfma<256, 1><<<gb, 256, 0, stream>>>(x, Wp, bl1, br1, xlr, N);
    k_prep<<<wb, 256, 0, stream>>>(xlr, att1, xlh, edl, N);
    k_gat_edge<1><<<wb, 256, 0, stream>>>(xlr, xlh, edl, att1, bias1, rowptr, csr, hbh, N);

    // ---- layer 2 ----
    k_wpack<<<((128 / 32) * 16 * 64 + 255) / 256, 256, 0, stream>>>(Wl2, Wr2, Wp, 128);
    k_gemm_mfma<128, 0><<<gb, 256, 0, stream>>>(hbh, Wp, bl2, br2, xlr, N);
    k_prep<<<wb, 256, 0, stream>>>(xlr, att2, xlh, edl, N);
    k_gat_edge<0><<<wb, 256, 0, stream>>>(xlr, xlh, edl, att2, bias2, rowptr, csr, hb, N);

    // ---- pool + head ----
    k_zero<<<(G * 129 + 255) / 256, 256, 0, stream>>>(poolg, G * 129);
    k_pool<<<(N + 31) / 32, 128, 0, stream>>>(hb, batch, pool, gcnt, N);
    k_head<<<G, 64, 0, stream>>>(pool, gcnt, Wlin, blin, (float*)d_out, G);
}

// Round 11
// 279.549 us; speedup vs baseline: 2.9355x; 1.1587x over previous
//
#include <hip/hip_runtime.h>
#include <hip/hip_fp16.h>
#include <math.h>
#include <stdint.h>

#define EPB 4096          // edges per block in partition kernels
#define NBKT 128          // dst>>9 buckets (98 used for N=50000)

typedef _Float16 f16x8 __attribute__((ext_vector_type(8)));
typedef float f32x4 __attribute__((ext_vector_type(4)));
typedef _Float16 h2 __attribute__((ext_vector_type(2)));

// ---------- 16-lane row sum via DPP (builtin: compiler handles hazards) ----
template<int CTRL>
__device__ __forceinline__ float dpp_add(float x) {
    union { float f; int i; } u, v;
    u.f = x;
    v.i = __builtin_amdgcn_update_dpp(0, u.i, CTRL, 0xF, 0xF, true);
    return x + v.f;
}
__device__ __forceinline__ float reduce16(float x) {
    x = dpp_add<0xB1>(x);   // quad_perm xor1
    x = dpp_add<0x4E>(x);   // quad_perm xor2
    x = dpp_add<0x124>(x);  // row_ror:4
    x = dpp_add<0x128>(x);  // row_ror:8
    return x;               // all 16 lanes of the row hold the row sum
}

// ---------- pack W (Wl|Wr) into MFMA B-frag order; PERM applies the paired
// K-permutation used by layer-2's input (k=2m -> c0(m), k=2m+1 -> c0(m)+16) --
template<int PERM>
__global__ void k_wpack(const float* __restrict__ Wl, const float* __restrict__ Wr,
                        _Float16* __restrict__ Wp, int K) {
    int t = blockIdx.x * 256 + threadIdx.x;
    int total = (K / 32) * 16 * 64;
    if (t >= total) return;
    int l = t & 63, ct = (t >> 6) & 15, kt = t >> 10;
    int col = ct * 16 + (l & 15);
    int k0 = kt * 32 + (l >> 4) * 8;
    const float* src = (col < 128) ? (Wl + (size_t)col * K)
                                   : (Wr + (size_t)(col - 128) * K);
    union { _Float16 h[8]; uint4 u; } o;
#pragma unroll
    for (int e = 0; e < 8; ++e) {
        int k = k0 + e, chan;
        if (PERM) {
            int m = k >> 1, hh = m >> 4, j = m & 15;
            int c0 = hh * 32 + j;
            chan = (k & 1) ? c0 + 16 : c0;
        } else chan = k;
        o.h[e] = (_Float16)src[chan];
    }
    reinterpret_cast<uint4*>(Wp)[t] = o.u;
}

// ---------- MFMA GEMM with fused prep epilogue ----------
// Waves 0,1 own xl cols (0..127): add bias, write fp16 PAIRS to xlh
// (slot h*16+j holds channels h*32+j, h*32+j+16) and edl=exp(0.6*att.xl).
// Waves 2,3 own xr cols: add bias, write paired float2 to xrp.
template<int K, int CVT>
__global__ __launch_bounds__(256) void k_gemm_mfma(
    const void* __restrict__ Xin, const _Float16* __restrict__ Wp,
    const float* __restrict__ bl, const float* __restrict__ br,
    const float* __restrict__ att,
    uint32_t* __restrict__ xlh, float2* __restrict__ xrp,
    float* __restrict__ edl, int N) {
    __shared__ _Float16 xs[32 * K];
    const int t = threadIdx.x, w = t >> 6, l = t & 63;
    const int row0 = blockIdx.x * 32;
    if (CVT) {
        const float* X = (const float*)Xin;
        for (int cid = t; cid < 32 * (K / 4); cid += 256) {
            int r = cid / (K / 4), c4 = (cid % (K / 4)) * 4;
            int gr = row0 + r;
            float4 v = make_float4(0.f, 0.f, 0.f, 0.f);
            if (gr < N) v = *reinterpret_cast<const float4*>(X + (size_t)gr * K + c4);
            h2 lo = {(_Float16)v.x, (_Float16)v.y};
            h2 hi = {(_Float16)v.z, (_Float16)v.w};
            uint2 pk;
            pk.x = __builtin_bit_cast(uint32_t, lo);
            pk.y = __builtin_bit_cast(uint32_t, hi);
            int ba = (r * K * 2 + c4 * 2) ^ ((r & 7) << 4);
            *reinterpret_cast<uint2*>(reinterpret_cast<char*>(xs) + ba) = pk;
        }
    } else {
        const _Float16* X = (const _Float16*)Xin;
        for (int cid = t; cid < 32 * (K / 8); cid += 256) {
            int r = cid / (K / 8), c8 = (cid % (K / 8)) * 8;
            int gr = row0 + r;
            uint4 v = make_uint4(0u, 0u, 0u, 0u);
            if (gr < N) v = *reinterpret_cast<const uint4*>(X + (size_t)gr * K + c8);
            int ba = (r * K * 2 + c8 * 2) ^ ((r & 7) << 4);
            *reinterpret_cast<uint4*>(reinterpret_cast<char*>(xs) + ba) = v;
        }
    }
    __syncthreads();
    f32x4 acc[2][4];
#pragma unroll
    for (int m = 0; m < 2; ++m)
#pragma unroll
        for (int n = 0; n < 4; ++n) acc[m][n] = (f32x4){0.f, 0.f, 0.f, 0.f};
#pragma unroll
    for (int kt = 0; kt < K / 32; ++kt) {
        f16x8 a[2], b[4];
#pragma unroll
        for (int m = 0; m < 2; ++m) {
            int r = m * 16 + (l & 15);
            int ba = (r * K * 2 + kt * 64 + (l >> 4) * 16) ^ ((r & 7) << 4);
            a[m] = *reinterpret_cast<const f16x8*>(reinterpret_cast<const char*>(xs) + ba);
        }
#pragma unroll
        for (int n = 0; n < 4; ++n) {
            int ct = w * 4 + n;
            b[n] = *reinterpret_cast<const f16x8*>(Wp + ((size_t)(kt * 16 + ct) * 64 + l) * 8);
        }
#pragma unroll
        for (int m = 0; m < 2; ++m)
#pragma unroll
            for (int n = 0; n < 4; ++n)
                acc[m][n] = __builtin_amdgcn_mfma_f32_16x16x32_f16(a[m], b[n], acc[m][n], 0, 0, 0);
    }
    const int j = l & 15;
    if (w < 2) {
        float attv[2][2], bv[2][2];
#pragma unroll
        for (int p = 0; p < 2; ++p) {
            int c0 = (2 * w + p) * 32 + j;
            attv[p][0] = att[c0]; attv[p][1] = att[c0 + 16];
            bv[p][0] = bl[c0];    bv[p][1] = bl[c0 + 16];
        }
#pragma unroll
        for (int m = 0; m < 2; ++m)
#pragma unroll
            for (int r4 = 0; r4 < 4; ++r4) {
                int gr = row0 + m * 16 + (l >> 4) * 4 + r4;
                bool ok = gr < N;
#pragma unroll
                for (int p = 0; p < 2; ++p) {
                    int h = 2 * w + p;
                    float v0 = acc[m][2 * p][r4] + bv[p][0];
                    float v1 = acc[m][2 * p + 1][r4] + bv[p][1];
                    float part = reduce16(fmaf(attv[p][0], v0, attv[p][1] * v1));
                    if (ok) {
                        h2 hp = {(_Float16)v0, (_Float16)v1};
                        xlh[(size_t)gr * 64 + h * 16 + j] = __builtin_bit_cast(uint32_t, hp);
                        if (j == 0) edl[gr * 4 + h] = __expf(0.6f * part);
                    }
                }
            }
    } else {
        float bv[2][2];
#pragma unroll
        for (int p = 0; p < 2; ++p) {
            int c0 = (2 * (w - 2) + p) * 32 + j;
            bv[p][0] = br[c0]; bv[p][1] = br[c0 + 16];
        }
#pragma unroll
        for (int m = 0; m < 2; ++m)
#pragma unroll
            for (int r4 = 0; r4 < 4; ++r4) {
                int gr = row0 + m * 16 + (l >> 4) * 4 + r4;
                if (gr < N) {
#pragma unroll
                    for (int p = 0; p < 2; ++p) {
                        int hh = 2 * (w - 2) + p;
                        float v0 = acc[m][2 * p][r4] + bv[p][0];
                        float v1 = acc[m][2 * p + 1][r4] + bv[p][1];
                        xrp[(size_t)gr * 64 + hh * 16 + j] = make_float2(v0, v1);
                    }
                }
            }
    }
}

// ---------------- radix partition by dst>>9 (scan-based, no global RMW) ----
__global__ __launch_bounds__(256) void k_hist(const int* __restrict__ dstArr,
                                              int* __restrict__ g_hist, int E) {
    __shared__ int h[NBKT];
    int t = threadIdx.x;
    if (t < NBKT) h[t] = 0;
    __syncthreads();
    int s0 = blockIdx.x * EPB, s1 = min(E, s0 + EPB);
    for (int i = s0 + t; i < s1; i += 256) atomicAdd(&h[dstArr[i] >> 9], 1);
    __syncthreads();
    if (t < NBKT) g_hist[blockIdx.x * NBKT + t] = h[t];
}
__global__ __launch_bounds__(512) void k_part_scan(const int* __restrict__ g_hist,
                                                   int* __restrict__ g_base,
                                                   int* __restrict__ bstart_out,
                                                   int NB1, int E) {
    __shared__ int csum[4][NBKT];
    __shared__ int btot[NBKT];
    __shared__ int bstart[NBKT];
    int tid = threadIdx.x, c = tid >> 7, b = tid & (NBKT - 1);
    int chunk = (NB1 + 3) >> 2;
    int i0 = c * chunk, i1 = min(NB1, i0 + chunk);
    int run = 0;
    for (int i = i0; i < i1; ++i) run += g_hist[i * NBKT + b];
    csum[c][b] = run;
    __syncthreads();
    int mytot = 0;
    if (c == 0) {
        mytot = csum[0][b] + csum[1][b] + csum[2][b] + csum[3][b];
        btot[b] = mytot;
    }
    __syncthreads();
    for (int off = 1; off < NBKT; off <<= 1) {
        int add = 0;
        if (c == 0 && b >= off) add = btot[b - off];
        __syncthreads();
        if (c == 0) btot[b] += add;
        __syncthreads();
    }
    if (c == 0) { bstart[b] = btot[b] - mytot; bstart_out[b] = bstart[b]; }
    if (tid == 0) bstart_out[NBKT] = E;
    __syncthreads();
    int base = bstart[b];
    for (int cc = 0; cc < c; ++cc) base += csum[cc][b];
    run = base;
    for (int i = i0; i < i1; ++i) {
        g_base[i * NBKT + b] = run;
        run += g_hist[i * NBKT + b];
    }
}
__global__ __launch_bounds__(256) void k_scatter(const int* __restrict__ ei,
                                                 const int* __restrict__ g_base,
                                                 uint32_t* __restrict__ tmp, int E) {
    __shared__ int off[NBKT];
    int t = threadIdx.x;
    if (t < NBKT) off[t] = g_base[blockIdx.x * NBKT + t];
    __syncthreads();
    int s0 = blockIdx.x * EPB, s1 = min(E, s0 + EPB);
    for (int i = s0 + t; i < s1; i += 256) {
        int s = ei[i], d = ei[E + i];
        int pos = atomicAdd(&off[d >> 9], 1);
        tmp[pos] = ((uint32_t)s << 16) | (uint32_t)d;
    }
}
// One block per 512-node bucket: LDS hist+scan -> rowptr, self-loops, and
// ordered edge placement, all within a ~67KB contiguous csr window.
__global__ __launch_bounds__(256) void k_bucket_csr(
    const uint32_t* __restrict__ tmp, const int* __restrict__ bstart,
    int* __restrict__ rowptr, int* __restrict__ csr, int N, int E) {
    __shared__ int cnt[512];
    __shared__ int fil[512];
    int b = blockIdx.x, t = threadIdx.x;
    int s0 = bstart[b], s1 = bstart[b + 1];
    cnt[t] = 0; cnt[t + 256] = 0;
    __syncthreads();
    for (int i = s0 + t; i < s1; i += 256)
        atomicAdd(&cnt[tmp[i] & 511], 1);
    __syncthreads();
    int c0 = cnt[t], c1 = cnt[t + 256];
    for (int off = 1; off < 512; off <<= 1) {
        int v0 = (t >= off) ? cnt[t - off] : 0;
        int v1 = (t + 256 >= off) ? cnt[t + 256 - off] : 0;
        __syncthreads();
        cnt[t] += v0; cnt[t + 256] += v1;
        __syncthreads();
    }
    int e0 = cnt[t] - c0, e1 = cnt[t + 256] - c1;   // exclusive
    __syncthreads();
    cnt[t] = e0; cnt[t + 256] = e1;
    fil[t] = 1; fil[t + 256] = 1;                   // slot 0 = self-loop
    __syncthreads();
    int n0 = b * 512;
#pragma unroll
    for (int k = 0; k < 2; ++k) {
        int ld = t + k * 256, n = n0 + ld;
        if (n < N) {
            int rp = s0 + cnt[ld] + n;              // edgesBefore + selfLoopsBefore
            rowptr[n] = rp;
            csr[rp] = n;
        }
    }
    if (b == 0 && t == 0) rowptr[N] = E + N;
    for (int i = s0 + t; i < s1; i += 256) {
        uint32_t pk = tmp[i];
        int d = (int)(pk & 0xFFFFu), ld = d & 511;
        int slot = atomicAdd(&fil[ld], 1);
        csr[s0 + cnt[ld] + d + slot] = (int)(pk >> 16);
    }
}

// ---------------- fused GATv2 edge kernel: one wave per node ----------------
// Wave-uniform n (readfirstlane) => rowptr/csr become scalar loads and the
// xlh/edl gathers use SGPR bases + constant lane voffsets (no VALU addr).
template<int OUT16>
__global__ __launch_bounds__(256) void k_gat_edge(
    const uint32_t* __restrict__ xlh, const float2* __restrict__ xrp,
    const float* __restrict__ edl, const float* __restrict__ att,
    const float* __restrict__ bias,
    const int* __restrict__ rowptr, const int* __restrict__ csr,
    void* __restrict__ out, int N) {
    const int l = threadIdx.x & 63;
    const int n = __builtin_amdgcn_readfirstlane(blockIdx.x * 4 + (threadIdx.x >> 6));
    if (n >= N) return;
    const int h = l >> 4, j = l & 15;
    const int c0 = h * 32 + j, c1 = c0 + 16;
    const float2 xr = xrp[(size_t)n * 64 + l];
    const float a04 = att[c0] * 0.4f, a14 = att[c1] * 0.4f;
    float ssum = 0.f, acc0 = 0.f, acc1 = 0.f;
    const int beg = rowptr[n], end = rowptr[n + 1];
    int i = beg;
    for (; i + 3 < end; i += 4) {
        int sv[4];
#pragma unroll
        for (int e = 0; e < 4; ++e) sv[e] = csr[i + e];
        uint32_t q[4]; float ev[4];
#pragma unroll
        for (int e = 0; e < 4; ++e) {
            q[e]  = xlh[(size_t)sv[e] * 64 + l];
            ev[e] = edl[sv[e] * 4 + h];
        }
#pragma unroll
        for (int e = 0; e < 4; ++e) {
            h2 A = __builtin_bit_cast(h2, q[e]);
            float A0 = (float)A.x, A1 = (float)A.y;
            float p = fabsf(A0 + xr.x) * a04;
            p = fmaf(fabsf(A1 + xr.y), a14, p);
            p = reduce16(p);
            float wgt = ev[e] * __expf(p);
            ssum += wgt;
            acc0 = fmaf(wgt, A0, acc0);
            acc1 = fmaf(wgt, A1, acc1);
        }
    }
    for (; i < end; ++i) {
        int s = csr[i];
        uint32_t q = xlh[(size_t)s * 64 + l];
        float ev = edl[s * 4 + h];
        h2 A = __builtin_bit_cast(h2, q);
        float A0 = (float)A.x, A1 = (float)A.y;
        float p = fabsf(A0 + xr.x) * a04;
        p = fmaf(fabsf(A1 + xr.y), a14, p);
        p = reduce16(p);
        float wgt = ev * __expf(p);
        ssum += wgt;
        acc0 = fmaf(wgt, A0, acc0);
        acc1 = fmaf(wgt, A1, acc1);
    }
    float inv = 1.f / ssum;
    float o0 = fmaf(acc0, inv, bias[c0]);
    float o1 = fmaf(acc1, inv, bias[c1]);
    if (OUT16) {   // layer 1: relu + fp16 pairs (feeds next GEMM via PERM wpack)
        o0 = fmaxf(o0, 0.f); o1 = fmaxf(o1, 0.f);
        h2 oh = {(_Float16)o0, (_Float16)o1};
        ((uint32_t*)out)[(size_t)n * 64 + l] = __builtin_bit_cast(uint32_t, oh);
    } else {       // layer 2: paired float2 for pooling
        ((float2*)out)[(size_t)n * 64 + l] = make_float2(o0, o1);
    }
}

// ---------------- pooling (slot-wise; channel perm handled in k_head) ------
__global__ void k_zero(float* __restrict__ p, int n) {
    int i = blockIdx.x * 256 + threadIdx.x;
    if (i < n) p[i] = 0.f;
}
__global__ __launch_bounds__(128) void k_pool(
    const float* __restrict__ h, const int* __restrict__ batch,
    float* __restrict__ pool, float* __restrict__ gcnt, int N) {
    const int NPB = 32;
    int c = threadIdx.x;
    int n0 = blockIdx.x * NPB;
    int n1 = min(n0 + NPB, N);
    float acc = 0.f;
    int curg = -1, cntl = 0;
    for (int n = n0; n < n1; ++n) {
        int g = batch[n];
        if (g != curg) {
            if (curg >= 0) {
                atomicAdd(&pool[curg * 128 + c], acc);
                if (c == 0) atomicAdd(&gcnt[curg], (float)cntl);
            }
            acc = 0.f; cntl = 0; curg = g;
        }
        acc += h[(size_t)n * 128 + c];
        cntl++;
    }
    if (curg >= 0) {
        atomicAdd(&pool[curg * 128 + c], acc);
        if (c == 0) atomicAdd(&gcnt[curg], (float)cntl);
    }
}
__global__ __launch_bounds__(64) void k_head(
    const float* __restrict__ pool, const float* __restrict__ gcnt,
    const float* __restrict__ Wlin, const float* __restrict__ blin,
    float* __restrict__ out, int G) {
    int g = blockIdx.x, l = threadIdx.x;
    float2 pv = ((const float2*)pool)[g * 64 + l];
    int c0 = (l >> 4) * 32 + (l & 15);
    float d = pv.x * Wlin[c0] + pv.y * Wlin[c0 + 16];
#pragma unroll
    for (int off = 32; off; off >>= 1) d += __shfl_xor(d, off, 64);
    if (l == 0) {
        float cnt = fmaxf(gcnt[g], 1.f);
        out[g] = d / cnt + blin[0];
    }
}

// ---------------- driver ----------------
extern "C" void kernel_launch(void* const* d_in, const int* in_sizes, int n_in,
                              void* d_out, int out_size, void* d_ws, size_t ws_size,
                              hipStream_t stream) {
    const float* x     = (const float*)d_in[0];
    const int*   ei    = (const int*)d_in[1];
    const int*   batch = (const int*)d_in[2];
    const float* Wl1   = (const float*)d_in[3];
    const float* bl1   = (const float*)d_in[4];
    const float* Wr1   = (const float*)d_in[5];
    const float* br1   = (const float*)d_in[6];
    const float* att1  = (const float*)d_in[7];
    const float* bias1 = (const float*)d_in[8];
    const float* Wl2   = (const float*)d_in[9];
    const float* bl2   = (const float*)d_in[10];
    const float* Wr2   = (const float*)d_in[11];
    const float* br2   = (const float*)d_in[12];
    const float* att2  = (const float*)d_in[13];
    const float* bias2 = (const float*)d_in[14];
    const float* Wlin  = (const float*)d_in[15];
    const float* blin  = (const float*)d_in[16];

    const int N   = in_sizes[2];
    const int E   = in_sizes[1] / 2;
    const int Fin = in_sizes[0] / N;     // 256
    const int G   = out_size;            // 64
    (void)n_in; (void)ws_size;

    char* p = (char*)d_ws;
    auto alloc = [&](size_t bytes) -> char* {
        char* r = p;
        p += (bytes + 255) & ~(size_t)255;
        return r;
    };
    uint32_t* xlh   = (uint32_t*)alloc((size_t)N * 64 * 4);  // xl fp16 pairs
    float2*   xrp   = (float2*)alloc((size_t)N * 64 * 8);    // xr fp32 pairs; aliases tmp
    uint32_t* hbh   = (uint32_t*)alloc((size_t)N * 64 * 4);  // layer1 out fp16 pairs
    float*    hbf   = (float*)alloc((size_t)N * 128 * 4);    // layer2 out fp32 pairs
    float*    edl   = (float*)alloc((size_t)N * 4 * 4);
    float*    wt    = (float*)alloc((size_t)Fin * 256 * 4);  // Wp fp16
    int*      rowptr= (int*)alloc((size_t)(N + 1) * 4);
    int*      csr   = (int*)alloc((size_t)(E + N) * 4);
    float*    poolg = (float*)alloc((size_t)G * 129 * 4);
    float*    pool  = poolg;
    float*    gcnt  = poolg + (size_t)G * 128;

    const int NB1 = (E + EPB - 1) / EPB;
    int*      g_hist = (int*)alloc((size_t)NB1 * NBKT * 4);
    int*      g_base = (int*)alloc((size_t)NB1 * NBKT * 4);
    int*      bstart = (int*)alloc((size_t)(NBKT + 1) * 4);
    uint32_t* tmp = (uint32_t*)xrp;   // CSR build finishes before gemm1 writes xrp
    _Float16* Wp  = (_Float16*)wt;

    const int wb = (N + 3) / 4;
    const int gb = (N + 31) / 32;

    // ---- CSR (bucketed radix partition + per-bucket build) ----
    k_hist<<<NB1, 256, 0, stream>>>(ei + E, g_hist, E);
    k_part_scan<<<1, 512, 0, stream>>>(g_hist, g_base, bstart, NB1, E);
    k_scatter<<<NB1, 256, 0, stream>>>(ei, g_base, tmp, E);
    k_bucket_csr<<<NBKT, 256, 0, stream>>>(tmp, bstart, rowptr, csr, N, E);

    // ---- layer 1 ----
    k_wpack<0><<<((Fin / 32) * 16 * 64 + 255) / 256, 256, 0, stream>>>(Wl1, Wr1, Wp, Fin);
    k_gemm_mfma<256, 1><<<gb, 256, 0, stream>>>(x, Wp, bl1, br1, att1, xlh, xrp, edl, N);
    k_gat_edge<1><<<wb, 256, 0, stream>>>(xlh, xrp, edl, att1, bias1, rowptr, csr, hbh, N);

    // ---- layer 2 (input is paired-K; wpack<1> applies matching perm) ----
    k_wpack<1><<<((128 / 32) * 16 * 64 + 255) / 256, 256, 0, stream>>>(Wl2, Wr2, Wp, 128);
    k_gemm_mfma<128, 0><<<gb, 256, 0, stream>>>(hbh, Wp, bl2, br2, att2, xlh, xrp, edl, N);
    k_gat_edge<0><<<wb, 256, 0, stream>>>(xlh, xrp, edl, att2, bias2, rowptr, csr, hbf, N);

    // ---- pool + head ----
    k_zero<<<(G * 129 + 255) / 256, 256, 0, stream>>>(poolg, G * 129);
    k_pool<<<(N + 31) / 32, 128, 0, stream>>>(hbf, batch, pool, gcnt, N);
    k_head<<<G, 64, 0, stream>>>(pool, gcnt, Wlin, blin, (float*)d_out, G);
}

// Round 12
// 274.157 us; speedup vs baseline: 2.9932x; 1.0197x over previous
//
#include <hip/hip_runtime.h>
#include <hip/hip_fp16.h>
#include <math.h>
#include <stdint.h>

#define EPB 4096          // edges per block in partition kernels
#define NBKT 128          // dst>>9 buckets (98 used for N=50000)

typedef _Float16 f16x8 __attribute__((ext_vector_type(8)));
typedef float f32x4 __attribute__((ext_vector_type(4)));
typedef float f32x2 __attribute__((ext_vector_type(2)));
typedef _Float16 h2 __attribute__((ext_vector_type(2)));

#define LOG2E 1.4426950f

__device__ __forceinline__ float fast_exp2(float x) {
#if __has_builtin(__builtin_amdgcn_exp2f)
    return __builtin_amdgcn_exp2f(x);
#else
    return __expf(x * 0.69314718f);
#endif
}

// ---------- 16-lane row sum via DPP (builtin: compiler handles hazards) ----
template<int CTRL>
__device__ __forceinline__ float dpp_add(float x) {
    union { float f; int i; } u, v;
    u.f = x;
    v.i = __builtin_amdgcn_update_dpp(0, u.i, CTRL, 0xF, 0xF, true);
    return x + v.f;
}
__device__ __forceinline__ float reduce16(float x) {
    x = dpp_add<0xB1>(x);   // quad_perm xor1
    x = dpp_add<0x4E>(x);   // quad_perm xor2
    x = dpp_add<0x124>(x);  // row_ror:4
    x = dpp_add<0x128>(x);  // row_ror:8
    return x;               // all 16 lanes of the row hold the row sum
}

// ---------- pack W (Wl|Wr) into MFMA B-frag order; PERM applies the paired
// K-permutation used by layer-2's input (k=2m -> c0(m), k=2m+1 -> c0(m)+16) --
template<int PERM>
__global__ void k_wpack(const float* __restrict__ Wl, const float* __restrict__ Wr,
                        _Float16* __restrict__ Wp, int K) {
    int t = blockIdx.x * 256 + threadIdx.x;
    int total = (K / 32) * 16 * 64;
    if (t >= total) return;
    int l = t & 63, ct = (t >> 6) & 15, kt = t >> 10;
    int col = ct * 16 + (l & 15);
    int k0 = kt * 32 + (l >> 4) * 8;
    const float* src = (col < 128) ? (Wl + (size_t)col * K)
                                   : (Wr + (size_t)(col - 128) * K);
    union { _Float16 h[8]; uint4 u; } o;
#pragma unroll
    for (int e = 0; e < 8; ++e) {
        int k = k0 + e, chan;
        if (PERM) {
            int m = k >> 1, hh = m >> 4, j = m & 15;
            int c0 = hh * 32 + j;
            chan = (k & 1) ? c0 + 16 : c0;
        } else chan = k;
        o.h[e] = (_Float16)src[chan];
    }
    reinterpret_cast<uint4*>(Wp)[t] = o.u;
}

// ---------- MFMA GEMM with fused prep epilogue ----------
// Waves 0,1 own xl cols: bias, fp16 PAIRS to xlh, ledl = 0.6*log2e*(att.xl).
// Waves 2,3 own xr cols: bias, paired float2 to xrp.
template<int K, int CVT>
__global__ __launch_bounds__(256) void k_gemm_mfma(
    const void* __restrict__ Xin, const _Float16* __restrict__ Wp,
    const float* __restrict__ bl, const float* __restrict__ br,
    const float* __restrict__ att,
    uint32_t* __restrict__ xlh, float2* __restrict__ xrp,
    float* __restrict__ ledl, int N) {
    __shared__ _Float16 xs[32 * K];
    const int t = threadIdx.x, w = t >> 6, l = t & 63;
    const int row0 = blockIdx.x * 32;
    if (CVT) {
        const float* X = (const float*)Xin;
        for (int cid = t; cid < 32 * (K / 4); cid += 256) {
            int r = cid / (K / 4), c4 = (cid % (K / 4)) * 4;
            int gr = row0 + r;
            float4 v = make_float4(0.f, 0.f, 0.f, 0.f);
            if (gr < N) v = *reinterpret_cast<const float4*>(X + (size_t)gr * K + c4);
            h2 lo = {(_Float16)v.x, (_Float16)v.y};
            h2 hi = {(_Float16)v.z, (_Float16)v.w};
            uint2 pk;
            pk.x = __builtin_bit_cast(uint32_t, lo);
            pk.y = __builtin_bit_cast(uint32_t, hi);
            int ba = (r * K * 2 + c4 * 2) ^ ((r & 7) << 4);
            *reinterpret_cast<uint2*>(reinterpret_cast<char*>(xs) + ba) = pk;
        }
    } else {
        const _Float16* X = (const _Float16*)Xin;
        for (int cid = t; cid < 32 * (K / 8); cid += 256) {
            int r = cid / (K / 8), c8 = (cid % (K / 8)) * 8;
            int gr = row0 + r;
            uint4 v = make_uint4(0u, 0u, 0u, 0u);
            if (gr < N) v = *reinterpret_cast<const uint4*>(X + (size_t)gr * K + c8);
            int ba = (r * K * 2 + c8 * 2) ^ ((r & 7) << 4);
            *reinterpret_cast<uint4*>(reinterpret_cast<char*>(xs) + ba) = v;
        }
    }
    __syncthreads();
    f32x4 acc[2][4];
#pragma unroll
    for (int m = 0; m < 2; ++m)
#pragma unroll
        for (int n = 0; n < 4; ++n) acc[m][n] = (f32x4){0.f, 0.f, 0.f, 0.f};
#pragma unroll
    for (int kt = 0; kt < K / 32; ++kt) {
        f16x8 a[2], b[4];
#pragma unroll
        for (int m = 0; m < 2; ++m) {
            int r = m * 16 + (l & 15);
            int ba = (r * K * 2 + kt * 64 + (l >> 4) * 16) ^ ((r & 7) << 4);
            a[m] = *reinterpret_cast<const f16x8*>(reinterpret_cast<const char*>(xs) + ba);
        }
#pragma unroll
        for (int n = 0; n < 4; ++n) {
            int ct = w * 4 + n;
            b[n] = *reinterpret_cast<const f16x8*>(Wp + ((size_t)(kt * 16 + ct) * 64 + l) * 8);
        }
#pragma unroll
        for (int m = 0; m < 2; ++m)
#pragma unroll
            for (int n = 0; n < 4; ++n)
                acc[m][n] = __builtin_amdgcn_mfma_f32_16x16x32_f16(a[m], b[n], acc[m][n], 0, 0, 0);
    }
    const int j = l & 15;
    if (w < 2) {
        float attv[2][2], bv[2][2];
#pragma unroll
        for (int p = 0; p < 2; ++p) {
            int c0 = (2 * w + p) * 32 + j;
            attv[p][0] = att[c0]; attv[p][1] = att[c0 + 16];
            bv[p][0] = bl[c0];    bv[p][1] = bl[c0 + 16];
        }
#pragma unroll
        for (int m = 0; m < 2; ++m)
#pragma unroll
            for (int r4 = 0; r4 < 4; ++r4) {
                int gr = row0 + m * 16 + (l >> 4) * 4 + r4;
                bool ok = gr < N;
#pragma unroll
                for (int p = 0; p < 2; ++p) {
                    int h = 2 * w + p;
                    float v0 = acc[m][2 * p][r4] + bv[p][0];
                    float v1 = acc[m][2 * p + 1][r4] + bv[p][1];
                    float part = reduce16(fmaf(attv[p][0], v0, attv[p][1] * v1));
                    if (ok) {
                        h2 hp = {(_Float16)v0, (_Float16)v1};
                        xlh[(size_t)gr * 64 + h * 16 + j] = __builtin_bit_cast(uint32_t, hp);
                        if (j == 0) ledl[gr * 4 + h] = 0.6f * LOG2E * part;
                    }
                }
            }
    } else {
        float bv[2][2];
#pragma unroll
        for (int p = 0; p < 2; ++p) {
            int c0 = (2 * (w - 2) + p) * 32 + j;
            bv[p][0] = br[c0]; bv[p][1] = br[c0 + 16];
        }
#pragma unroll
        for (int m = 0; m < 2; ++m)
#pragma unroll
            for (int r4 = 0; r4 < 4; ++r4) {
                int gr = row0 + m * 16 + (l >> 4) * 4 + r4;
                if (gr < N) {
#pragma unroll
                    for (int p = 0; p < 2; ++p) {
                        int hh = 2 * (w - 2) + p;
                        float v0 = acc[m][2 * p][r4] + bv[p][0];
                        float v1 = acc[m][2 * p + 1][r4] + bv[p][1];
                        xrp[(size_t)gr * 64 + hh * 16 + j] = make_float2(v0, v1);
                    }
                }
            }
    }
}

// ---------------- radix partition by dst>>9 (scan-based, no global RMW) ----
__global__ __launch_bounds__(256) void k_hist(const int* __restrict__ dstArr,
                                              int* __restrict__ g_hist, int E) {
    __shared__ int h[NBKT];
    int t = threadIdx.x;
    if (t < NBKT) h[t] = 0;
    __syncthreads();
    int s0 = blockIdx.x * EPB, s1 = min(E, s0 + EPB);
    for (int i = s0 + t; i < s1; i += 256) atomicAdd(&h[dstArr[i] >> 9], 1);
    __syncthreads();
    if (t < NBKT) g_hist[blockIdx.x * NBKT + t] = h[t];
}
__global__ __launch_bounds__(512) void k_part_scan(const int* __restrict__ g_hist,
                                                   int* __restrict__ g_base,
                                                   int* __restrict__ bstart_out,
                                                   int NB1, int E) {
    __shared__ int csum[4][NBKT];
    __shared__ int btot[NBKT];
    __shared__ int bstart[NBKT];
    int tid = threadIdx.x, c = tid >> 7, b = tid & (NBKT - 1);
    int chunk = (NB1 + 3) >> 2;
    int i0 = c * chunk, i1 = min(NB1, i0 + chunk);
    int run = 0;
    for (int i = i0; i < i1; ++i) run += g_hist[i * NBKT + b];
    csum[c][b] = run;
    __syncthreads();
    int mytot = 0;
    if (c == 0) {
        mytot = csum[0][b] + csum[1][b] + csum[2][b] + csum[3][b];
        btot[b] = mytot;
    }
    __syncthreads();
    for (int off = 1; off < NBKT; off <<= 1) {
        int add = 0;
        if (c == 0 && b >= off) add = btot[b - off];
        __syncthreads();
        if (c == 0) btot[b] += add;
        __syncthreads();
    }
    if (c == 0) { bstart[b] = btot[b] - mytot; bstart_out[b] = bstart[b]; }
    if (tid == 0) bstart_out[NBKT] = E;
    __syncthreads();
    int base = bstart[b];
    for (int cc = 0; cc < c; ++cc) base += csum[cc][b];
    run = base;
    for (int i = i0; i < i1; ++i) {
        g_base[i * NBKT + b] = run;
        run += g_hist[i * NBKT + b];
    }
}
__global__ __launch_bounds__(256) void k_scatter(const int* __restrict__ ei,
                                                 const int* __restrict__ g_base,
                                                 uint32_t* __restrict__ tmp, int E) {
    __shared__ int off[NBKT];
    int t = threadIdx.x;
    if (t < NBKT) off[t] = g_base[blockIdx.x * NBKT + t];
    __syncthreads();
    int s0 = blockIdx.x * EPB, s1 = min(E, s0 + EPB);
    for (int i = s0 + t; i < s1; i += 256) {
        int s = ei[i], d = ei[E + i];
        int pos = atomicAdd(&off[d >> 9], 1);
        tmp[pos] = ((uint32_t)s << 16) | (uint32_t)d;
    }
}
// One block per 512-node bucket: LDS hist+scan -> rowptr, self-loops, and
// ordered edge placement, all within a ~67KB contiguous csr window.
__global__ __launch_bounds__(256) void k_bucket_csr(
    const uint32_t* __restrict__ tmp, const int* __restrict__ bstart,
    int* __restrict__ rowptr, int* __restrict__ csr, int N, int E) {
    __shared__ int cnt[512];
    __shared__ int fil[512];
    int b = blockIdx.x, t = threadIdx.x;
    int s0 = bstart[b], s1 = bstart[b + 1];
    cnt[t] = 0; cnt[t + 256] = 0;
    __syncthreads();
    for (int i = s0 + t; i < s1; i += 256)
        atomicAdd(&cnt[tmp[i] & 511], 1);
    __syncthreads();
    int c0 = cnt[t], c1 = cnt[t + 256];
    for (int off = 1; off < 512; off <<= 1) {
        int v0 = (t >= off) ? cnt[t - off] : 0;
        int v1 = (t + 256 >= off) ? cnt[t + 256 - off] : 0;
        __syncthreads();
        cnt[t] += v0; cnt[t + 256] += v1;
        __syncthreads();
    }
    int e0 = cnt[t] - c0, e1 = cnt[t + 256] - c1;   // exclusive
    __syncthreads();
    cnt[t] = e0; cnt[t + 256] = e1;
    fil[t] = 1; fil[t + 256] = 1;                   // slot 0 = self-loop
    __syncthreads();
    int n0 = b * 512;
#pragma unroll
    for (int k = 0; k < 2; ++k) {
        int ld = t + k * 256, n = n0 + ld;
        if (n < N) {
            int rp = s0 + cnt[ld] + n;              // edgesBefore + selfLoopsBefore
            rowptr[n] = rp;
            csr[rp] = n;
        }
    }
    if (b == 0 && t == 0) rowptr[N] = E + N;
    for (int i = s0 + t; i < s1; i += 256) {
        uint32_t pk = tmp[i];
        int d = (int)(pk & 0xFFFFu), ld = d & 511;
        int slot = atomicAdd(&fil[ld], 1);
        csr[s0 + cnt[ld] + d + slot] = (int)(pk >> 16);
    }
}

// ---------------- fused GATv2 edge kernel: one wave per node ----------------
// w_e = exp2( reduce16(0.4*L*att.|xl_s+xr_d|) + ledl_s ).  Source indices are
// forced into SGPRs (readfirstlane) so gathers use saddr + const lane voffset.
template<int OUT16>
__global__ __launch_bounds__(256) void k_gat_edge(
    const uint32_t* __restrict__ xlh, const float2* __restrict__ xrp,
    const float* __restrict__ ledl, const float* __restrict__ att,
    const float* __restrict__ bias,
    const int* __restrict__ rowptr, const int* __restrict__ csr,
    void* __restrict__ out, int N) {
    const int l = threadIdx.x & 63;
    const int n = __builtin_amdgcn_readfirstlane(blockIdx.x * 4 + (threadIdx.x >> 6));
    if (n >= N) return;
    const int h = l >> 4, j = l & 15;
    const int c0 = h * 32 + j, c1 = c0 + 16;
    const float2 xrv = xrp[(size_t)n * 64 + l];
    const f32x2 xr2 = {xrv.x, xrv.y};
    const float a04 = att[c0] * (0.4f * LOG2E), a14 = att[c1] * (0.4f * LOG2E);
    f32x2 acc2 = {0.f, 0.f};
    float ssum = 0.f;
    const int beg = rowptr[n], end = rowptr[n + 1];
    int i = beg;
    for (; i + 7 < end; i += 8) {
        int sr[8];
#pragma unroll
        for (int e = 0; e < 8; ++e) sr[e] = __builtin_amdgcn_readfirstlane(csr[i + e]);
        uint32_t q[8]; float lv[8];
#pragma unroll
        for (int e = 0; e < 8; ++e) {
            q[e]  = xlh[(size_t)(uint32_t)sr[e] * 64 + l];
            lv[e] = ledl[(uint32_t)sr[e] * 4 + h];
        }
#pragma unroll
        for (int e = 0; e < 8; ++e) {
            h2 A = __builtin_bit_cast(h2, q[e]);
            f32x2 A2 = {(float)A.x, (float)A.y};
            f32x2 t2 = A2 + xr2;
            float p = fmaf(fabsf(t2.y), a14, fabsf(t2.x) * a04);
            p = reduce16(p);
            float w = fast_exp2(p + lv[e]);
            ssum += w;
            acc2 = __builtin_elementwise_fma((f32x2){w, w}, A2, acc2);
        }
    }
    for (; i < end; ++i) {
        int s = __builtin_amdgcn_readfirstlane(csr[i]);
        uint32_t q = xlh[(size_t)(uint32_t)s * 64 + l];
        float lv  = ledl[(uint32_t)s * 4 + h];
        h2 A = __builtin_bit_cast(h2, q);
        f32x2 A2 = {(float)A.x, (float)A.y};
        f32x2 t2 = A2 + xr2;
        float p = fmaf(fabsf(t2.y), a14, fabsf(t2.x) * a04);
        p = reduce16(p);
        float w = fast_exp2(p + lv);
        ssum += w;
        acc2 = __builtin_elementwise_fma((f32x2){w, w}, A2, acc2);
    }
    float inv = 1.f / ssum;
    float o0 = fmaf(acc2.x, inv, bias[c0]);
    float o1 = fmaf(acc2.y, inv, bias[c1]);
    if (OUT16) {   // layer 1: relu + fp16 pairs (feeds next GEMM via PERM wpack)
        o0 = fmaxf(o0, 0.f); o1 = fmaxf(o1, 0.f);
        h2 oh = {(_Float16)o0, (_Float16)o1};
        ((uint32_t*)out)[(size_t)n * 64 + l] = __builtin_bit_cast(uint32_t, oh);
    } else {       // layer 2: paired float2 for pooling
        ((float2*)out)[(size_t)n * 64 + l] = make_float2(o0, o1);
    }
}

// ---------------- pooling (slot-wise; channel perm handled in k_head) ------
__global__ void k_zero(float* __restrict__ p, int n) {
    int i = blockIdx.x * 256 + threadIdx.x;
    if (i < n) p[i] = 0.f;
}
__global__ __launch_bounds__(128) void k_pool(
    const float* __restrict__ h, const int* __restrict__ batch,
    float* __restrict__ pool, float* __restrict__ gcnt, int N) {
    const int NPB = 32;
    int c = threadIdx.x;
    int n0 = blockIdx.x * NPB;
    int n1 = min(n0 + NPB, N);
    float acc = 0.f;
    int curg = -1, cntl = 0;
    for (int n = n0; n < n1; ++n) {
        int g = batch[n];
        if (g != curg) {
            if (curg >= 0) {
                atomicAdd(&pool[curg * 128 + c], acc);
                if (c == 0) atomicAdd(&gcnt[curg], (float)cntl);
            }
            acc = 0.f; cntl = 0; curg = g;
        }
        acc += h[(size_t)n * 128 + c];
        cntl++;
    }
    if (curg >= 0) {
        atomicAdd(&pool[curg * 128 + c], acc);
        if (c == 0) atomicAdd(&gcnt[curg], (float)cntl);
    }
}
__global__ __launch_bounds__(64) void k_head(
    const float* __restrict__ pool, const float* __restrict__ gcnt,
    const float* __restrict__ Wlin, const float* __restrict__ blin,
    float* __restrict__ out, int G) {
    int g = blockIdx.x, l = threadIdx.x;
    float2 pv = ((const float2*)pool)[g * 64 + l];
    int c0 = (l >> 4) * 32 + (l & 15);
    float d = pv.x * Wlin[c0] + pv.y * Wlin[c0 + 16];
#pragma unroll
    for (int off = 32; off; off >>= 1) d += __shfl_xor(d, off, 64);
    if (l == 0) {
        float cnt = fmaxf(gcnt[g], 1.f);
        out[g] = d / cnt + blin[0];
    }
}

// ---------------- driver ----------------
extern "C" void kernel_launch(void* const* d_in, const int* in_sizes, int n_in,
                              void* d_out, int out_size, void* d_ws, size_t ws_size,
                              hipStream_t stream) {
    const float* x     = (const float*)d_in[0];
    const int*   ei    = (const int*)d_in[1];
    const int*   batch = (const int*)d_in[2];
    const float* Wl1   = (const float*)d_in[3];
    const float* bl1   = (const float*)d_in[4];
    const float* Wr1   = (const float*)d_in[5];
    const float* br1   = (const float*)d_in[6];
    const float* att1  = (const float*)d_in[7];
    const float* bias1 = (const float*)d_in[8];
    const float* Wl2   = (const float*)d_in[9];
    const float* bl2   = (const float*)d_in[10];
    const float* Wr2   = (const float*)d_in[11];
    const float* br2   = (const float*)d_in[12];
    const float* att2  = (const float*)d_in[13];
    const float* bias2 = (const float*)d_in[14];
    const float* Wlin  = (const float*)d_in[15];
    const float* blin  = (const float*)d_in[16];

    const int N   = in_sizes[2];
    const int E   = in_sizes[1] / 2;
    const int Fin = in_sizes[0] / N;     // 256
    const int G   = out_size;            // 64
    (void)n_in; (void)ws_size;

    char* p = (char*)d_ws;
    auto alloc = [&](size_t bytes) -> char* {
        char* r = p;
        p += (bytes + 255) & ~(size_t)255;
        return r;
    };
    uint32_t* xlh   = (uint32_t*)alloc((size_t)N * 64 * 4);  // xl fp16 pairs
    float2*   xrp   = (float2*)alloc((size_t)N * 64 * 8);    // xr fp32 pairs; aliases tmp
    uint32_t* hbh   = (uint32_t*)alloc((size_t)N * 64 * 4);  // layer1 out fp16 pairs
    float*    hbf   = (float*)alloc((size_t)N * 128 * 4);    // layer2 out fp32 pairs
    float*    ledl  = (float*)alloc((size_t)N * 4 * 4);
    float*    wt    = (float*)alloc((size_t)Fin * 256 * 4);  // Wp fp16
    int*      rowptr= (int*)alloc((size_t)(N + 1) * 4);
    int*      csr   = (int*)alloc((size_t)(E + N) * 4);
    float*    poolg = (float*)alloc((size_t)G * 129 * 4);
    float*    pool  = poolg;
    float*    gcnt  = poolg + (size_t)G * 128;

    const int NB1 = (E + EPB - 1) / EPB;
    int*      g_hist = (int*)alloc((size_t)NB1 * NBKT * 4);
    int*      g_base = (int*)alloc((size_t)NB1 * NBKT * 4);
    int*      bstart = (int*)alloc((size_t)(NBKT + 1) * 4);
    uint32_t* tmp = (uint32_t*)xrp;   // CSR build finishes before gemm1 writes xrp
    _Float16* Wp  = (_Float16*)wt;

    const int wb = (N + 3) / 4;
    const int gb = (N + 31) / 32;

    // ---- CSR (bucketed radix partition + per-bucket build) ----
    k_hist<<<NB1, 256, 0, stream>>>(ei + E, g_hist, E);
    k_part_scan<<<1, 512, 0, stream>>>(g_hist, g_base, bstart, NB1, E);
    k_scatter<<<NB1, 256, 0, stream>>>(ei, g_base, tmp, E);
    k_bucket_csr<<<NBKT, 256, 0, stream>>>(tmp, bstart, rowptr, csr, N, E);

    // ---- layer 1 ----
    k_wpack<0><<<((Fin / 32) * 16 * 64 + 255) / 256, 256, 0, stream>>>(Wl1, Wr1, Wp, Fin);
    k_gemm_mfma<256, 1><<<gb, 256, 0, stream>>>(x, Wp, bl1, br1, att1, xlh, xrp, ledl, N);
    k_gat_edge<1><<<wb, 256, 0, stream>>>(xlh, xrp, ledl, att1, bias1, rowptr, csr, hbh, N);

    // ---- layer 2 (input is paired-K; wpack<1> applies matching perm) ----
    k_wpack<1><<<((128 / 32) * 16 * 64 + 255) / 256, 256, 0, stream>>>(Wl2, Wr2, Wp, 128);
    k_gemm_mfma<128, 0><<<gb, 256, 0, stream>>>(hbh, Wp, bl2, br2, att2, xlh, xrp, ledl, N);
    k_gat_edge<0><<<wb, 256, 0, stream>>>(xlh, xrp, ledl, att2, bias2, rowptr, csr, hbf, N);

    // ---- pool + head ----
    k_zero<<<(G * 129 + 255) / 256, 256, 0, stream>>>(poolg, G * 129);
    k_pool<<<(N + 31) / 32, 128, 0, stream>>>(hbf, batch, pool, gcnt, N);
    k_head<<<G, 64, 0, stream>>>(pool, gcnt, Wlin, blin, (float*)d_out, G);
}